// Round 22
// baseline (173.373 us; speedup 1.0000x reference)
//
#include <hip/hip_runtime.h>
#include <hip/hip_bf16.h>

#define N_PTS 50000
#define H_NB 32
#define K_KP 15
#define C_IN 64
#define C_OUT 128
#define KC 960           // K_KP * C_IN
#define M_PAD 50048      // padded wf rows (mult of 64)
#define M_TILE 32
#define PPW 8            // points per wave (4 waves/block)
#define WFS 968          // fused-path wf_lds row stride
#define XG_SUB 68        // fused-path xg strides
#define XG_PLANE 552
#define XG_WAVE (4*XG_PLANE)
#define XPB ((N_PTS*C_IN/8 + 255)/256)   // xprep blocks = 1563
#define BN_EPS 1e-5f
#define SLOPE 0.2f

typedef __attribute__((ext_vector_type(8))) __bf16 bf16x8;
typedef __attribute__((ext_vector_type(8))) unsigned short ushort8;
typedef __attribute__((ext_vector_type(4))) float f32x4;

__device__ __forceinline__ unsigned short bfbits(float f){
  return __builtin_bit_cast(unsigned short, (__bf16)f);
}
__device__ __forceinline__ bf16x8 ld_bf8(const unsigned short* p){
  return __builtin_bit_cast(bf16x8, *(const uint4*)p);
}
// async global->LDS DMA, 16B per lane (gemm staging)
__device__ __forceinline__ void gload16(const void* g, void* l){
  __builtin_amdgcn_global_load_lds(
      (__attribute__((address_space(1))) void*)(g),
      (__attribute__((address_space(3))) void*)(l), 16, 0, 0);
}

// ---- prep: [blocks 0..XPB): x f32->bf16 RNE; [XPB..XPB+120): W transpose; zeros stats ----
__global__ __launch_bounds__(256) void prep_kernel(const float* __restrict__ W,
                                                   const float* __restrict__ x,
                                                   unsigned short* __restrict__ Wt,
                                                   unsigned short* __restrict__ xbf,
                                                   float* __restrict__ stats){
  __shared__ float tile[32][33];
  int b = blockIdx.x;
  if (b < XPB) {
    int t = b*256 + threadIdx.x;
    if (t < N_PTS*C_IN/8) {
      float4 a = ((const float4*)x)[2*t], v = ((const float4*)x)[2*t+1];
      ushort8 o;
      o[0]=bfbits(a.x); o[1]=bfbits(a.y); o[2]=bfbits(a.z); o[3]=bfbits(a.w);
      o[4]=bfbits(v.x); o[5]=bfbits(v.y); o[6]=bfbits(v.z); o[7]=bfbits(v.w);
      *(ushort8*)(xbf + 8*t) = o;
    }
    return;
  }
  b -= XPB;
  const int kc0 = (b % (KC/32)) * 32, d0 = (b / (KC/32)) * 32;
  if (kc0 == 0 && d0 == 0 && threadIdx.x < 2*C_OUT)
    stats[threadIdx.x] = 0.f;
  const int r = threadIdx.x >> 5, c = threadIdx.x & 31;
  #pragma unroll
  for (int rr = 0; rr < 4; ++rr) {
    int row = rr*8 + r;
    tile[row][c] = W[(size_t)(kc0+row)*C_OUT + d0 + c];
  }
  __syncthreads();
  #pragma unroll
  for (int rr = 0; rr < 4; ++rr) {
    int dr = rr*8 + r;
    Wt[(size_t)(d0+dr)*KC + kc0 + c] = bfbits(tile[c][dr]);
  }
}

// ---- core: Phase A. SPLIT: reg-staged gather (2-deep prefetch), wf->global.
//      !SPLIT: legacy fused (R7-verified). ----
template<bool SPLIT>
__global__ __launch_bounds__(256, SPLIT ? 5 : 2) void kpconv_core(
    const float* __restrict__ points,
    const float* __restrict__ x,            // f32 x (fused path)
    const unsigned short* __restrict__ xbf, // bf16 x (split path)
    const int*   __restrict__ neighbors,
    const float* __restrict__ kpts,
    const unsigned short* __restrict__ Wt,
    unsigned short* __restrict__ wfg,
    float* __restrict__ out_pre,
    float* __restrict__ stats)
{
  // SPLIT: single 4KB buffer/wave: row h (64 elems), phys chunk pc holds logical pc^(2*(h>>3))
  __shared__ __align__(16) unsigned short xg[SPLIT ? 4*2048 : 4*XG_WAVE];
  __shared__ unsigned short wf_lds[SPLIT ? 8 : M_TILE*WFS];
  __shared__ float sh_sum[SPLIT ? 1 : C_OUT];
  __shared__ float sh_sq [SPLIT ? 1 : C_OUT];

  const int tid  = threadIdx.x;
  const int w    = tid >> 6;
  const int lane = tid & 63;
  const int l15  = lane & 15;
  const int lq   = lane >> 4;
  const int base = blockIdx.x * M_TILE;

  float kqx, kqy, kqz;
  if (l15 < K_KP) { kqx = kpts[l15*3+0]; kqy = kpts[l15*3+1]; kqz = kpts[l15*3+2]; }
  else            { kqx = 1e3f; kqy = 0.f; kqz = 0.f; }

  if constexpr (SPLIT) {
    unsigned short* xbuf = &xg[w * 2048];
    const int r8 = lane >> 3;
    const int pc = lane & 7;

    int   idx0, idx1 = 0, idx2 = 0, idx3 = 0;
    float c0x, c0y, c0z, c1x = 0, c1y = 0, c1z = 0;
    float c2x = 0, c2y = 0, c2z = 0, c3x = 0, c3y = 0, c3z = 0;
    float p0x, p0y, p0z, p1x = 0, p1y = 0, p1z = 0;   // npos for p, p+1
    uint4 xrA[4], xrB[4];

    // prologue: idx/center 0..2, npos 0..1, x-prefetch 0,1
    {
      int n0 = base + w*PPW;
      int nc0 = n0 < N_PTS ? n0 : N_PTS-1;
      idx0 = neighbors[nc0*H_NB + (lane & 31)];
      c0x = points[nc0*3+0]; c0y = points[nc0*3+1]; c0z = points[nc0*3+2];
      const float* pp = points + (size_t)idx0*3;
      p0x = pp[0]; p0y = pp[1]; p0z = pp[2];
      int nc1 = (n0+1) < N_PTS ? (n0+1) : N_PTS-1;
      idx1 = neighbors[nc1*H_NB + (lane & 31)];
      c1x = points[nc1*3+0]; c1y = points[nc1*3+1]; c1z = points[nc1*3+2];
      const float* pq = points + (size_t)idx1*3;
      p1x = pq[0]; p1y = pq[1]; p1z = pq[2];
      int nc2 = (n0+2) < N_PTS ? (n0+2) : N_PTS-1;
      idx2 = neighbors[nc2*H_NB + (lane & 31)];
      c2x = points[nc2*3+0]; c2y = points[nc2*3+1]; c2z = points[nc2*3+2];
      #pragma unroll
      for (int it = 0; it < 4; ++it) {
        int nh = __shfl(idx0, 8*it + r8);
        xrA[it] = *(const uint4*)(xbf + (size_t)nh*C_IN + ((pc ^ (2*it)) * 8));
      }
      #pragma unroll
      for (int it = 0; it < 4; ++it) {
        int nh = __shfl(idx1, 8*it + r8);
        xrB[it] = *(const uint4*)(xbf + (size_t)nh*C_IN + ((pc ^ (2*it)) * 8));
      }
    }

    #pragma unroll 2
    for (int p = 0; p < PPW; ++p) {
      // 1. stage current x -> LDS (linear 16B/lane, conflict-free), xr freed
      // 2. refill the same xr regs with x(p+2) (2-deep register prefetch)
      if ((p & 1) == 0) {
        #pragma unroll
        for (int it = 0; it < 4; ++it)
          *(uint4*)(xbuf + it*512 + lane*8) = xrA[it];
        if (p + 2 < PPW) {
          #pragma unroll
          for (int it = 0; it < 4; ++it) {
            int nh = __shfl(idx2, 8*it + r8);
            xrA[it] = *(const uint4*)(xbf + (size_t)nh*C_IN + ((pc ^ (2*it)) * 8));
          }
        }
      } else {
        #pragma unroll
        for (int it = 0; it < 4; ++it)
          *(uint4*)(xbuf + it*512 + lane*8) = xrB[it];
        if (p + 2 < PPW) {
          #pragma unroll
          for (int it = 0; it < 4; ++it) {
            int nh = __shfl(idx2, 8*it + r8);
            xrB[it] = *(const uint4*)(xbf + (size_t)nh*C_IN + ((pc ^ (2*it)) * 8));
          }
        }
      }

      // 3. idx/center for p+3
      if (p + 3 < PPW) {
        int n3 = base + w*PPW + p + 3;
        int nc3 = n3 < N_PTS ? n3 : N_PTS-1;
        idx3 = neighbors[nc3*H_NB + (lane & 31)];
        c3x = points[nc3*3+0]; c3y = points[nc3*3+1]; c3z = points[nc3*3+2];
      }

      // 4. influence A-frag from npos(p)
      float rx = p0x - c0x, ry = p0y - c0y, rz = p0z - c0z;
      bf16x8 afrag;
      #pragma unroll
      for (int j = 0; j < 8; ++j) {
        int h = (lq << 3) + j;
        float dx = __shfl(rx, h) - kqx;
        float dy = __shfl(ry, h) - kqy;
        float dz = __shfl(rz, h) - kqz;
        float f  = 1.f - sqrtf(dx*dx + dy*dy + dz*dz);
        afrag[j] = (__bf16)(f > 0.f ? f : 0.f);
      }

      // 5. staging writes visible before cross-lane reads
      asm volatile("s_waitcnt lgkmcnt(0)" ::: "memory");
      __builtin_amdgcn_sched_barrier(0);

      // 6. B-frag reads (R21-proven conflict-free) + MFMA
      f32x4 acc[4] = {{0,0,0,0},{0,0,0,0},{0,0,0,0},{0,0,0,0}};
      #pragma unroll
      for (int ct = 0; ct < 4; ++ct) {
        ushort8 bb;
        const int pcr = ((2*ct + (l15 >> 3)) ^ (2*lq)) * 8 + (l15 & 7);
        #pragma unroll
        for (int j = 0; j < 8; ++j)
          bb[j] = xbuf[lq*512 + j*64 + pcr];
        acc[ct] = __builtin_amdgcn_mfma_f32_16x16x32_bf16(
            afrag, __builtin_bit_cast(bf16x8, bb), acc[ct], 0, 0, 0);
      }

      // 7. bounce acc -> xbuf (k-stride 72; x data already consumed)
      const int n_out = base + w*PPW + p;
      #pragma unroll
      for (int ct = 0; ct < 4; ++ct) {
        #pragma unroll
        for (int r = 0; r < 4; ++r) {
          int k = 4*lq + r;
          if (k < K_KP)
            xbuf[72*k + ct*16 + l15] = bfbits(acc[ct][r]);
        }
      }
      asm volatile("s_waitcnt lgkmcnt(0)" ::: "memory");
      // 8. coalesced 16B stores to wfg
      if (n_out < N_PTS) {
        uint4 s0 = *(const uint4*)(xbuf + 72*(lane>>3) + 8*(lane&7));
        *(uint4*)(wfg + (size_t)n_out*KC + lane*8) = s0;
        if (lane < 56) {
          int ch = 64 + lane;
          uint4 s1 = *(const uint4*)(xbuf + 72*(ch>>3) + 8*(ch&7));
          *(uint4*)(wfg + (size_t)n_out*KC + ch*8) = s1;
        }
      }
      asm volatile("s_waitcnt lgkmcnt(0)" ::: "memory");

      // 9. rotate pipeline; npos for new p+1
      idx0 = idx1; idx1 = idx2; idx2 = idx3;
      c0x = c1x; c0y = c1y; c0z = c1z;
      c1x = c2x; c1y = c2y; c1z = c2z;
      c2x = c3x; c2y = c3y; c2z = c3z;
      p0x = p1x; p0y = p1y; p0z = p1z;
      if (p + 2 < PPW) {
        const float* pq = points + (size_t)idx1*3;
        p1x = pq[0]; p1y = pq[1]; p1z = pq[2];
      }
    }
  } else {
    // ------------- legacy fused path (R7-verified), f32 x -------------
    unsigned short* xgw = &xg[w * XG_WAVE];
    {
      int   idx_c, idx_n = 0, idx_nn = 0;
      float pcx, pcy, pcz, pnx = 0, pny = 0, pnz = 0;
      float ccx, ccy, ccz, cnx = 0, cny = 0, cnz = 0, c2x = 0, c2y = 0, c2z = 0;
      float4 xr[8];
      {
        int n0 = base + w*PPW;  int nc0 = n0 < N_PTS ? n0 : N_PTS-1;
        idx_c = neighbors[nc0*H_NB + (lane & 31)];
        ccx = points[nc0*3+0]; ccy = points[nc0*3+1]; ccz = points[nc0*3+2];
        const float* pp = points + (size_t)idx_c*3;
        pcx = pp[0]; pcy = pp[1]; pcz = pp[2];
        #pragma unroll
        for (int it = 0; it < 8; ++it) {
          int nh = __shfl(idx_c, 4*it + lq);
          xr[it] = *(const float4*)&x[(size_t)nh*C_IN + 4*l15];
        }
        int n1 = n0 + 1;  int nc1 = n1 < N_PTS ? n1 : N_PTS-1;
        idx_n = neighbors[nc1*H_NB + (lane & 31)];
        cnx = points[nc1*3+0]; cny = points[nc1*3+1]; cnz = points[nc1*3+2];
        const float* pq = points + (size_t)idx_n*3;
        pnx = pq[0]; pny = pq[1]; pnz = pq[2];
      }

      #pragma unroll 1
      for (int p = 0; p < PPW; ++p) {
        const int mpt = w*PPW + p;
        float rx = pcx - ccx, ry = pcy - ccy, rz = pcz - ccz;
        bf16x8 afrag;
        #pragma unroll
        for (int j = 0; j < 8; ++j) {
          int h = (lq << 3) + j;
          float dx = __shfl(rx, h) - kqx;
          float dy = __shfl(ry, h) - kqy;
          float dz = __shfl(rz, h) - kqz;
          float f  = 1.f - sqrtf(dx*dx + dy*dy + dz*dz);
          afrag[j] = (__bf16)(f > 0.f ? f : 0.f);
        }
        #pragma unroll
        for (int it = 0; it < 8; ++it) {
          float4 v = xr[it];
          unsigned lo = ((unsigned)bfbits(v.y) << 16) | bfbits(v.x);
          unsigned hi = ((unsigned)bfbits(v.w) << 16) | bfbits(v.z);
          int ei = XG_PLANE*(l15 >> 2) + XG_SUB*it + 16*lq + 4*(l15 & 3);
          uint2 val; val.x = lo; val.y = hi;
          *(uint2*)(xgw + ei) = val;
        }
        if (p + 1 < PPW) {
          #pragma unroll
          for (int it = 0; it < 8; ++it) {
            int nh = __shfl(idx_n, 4*it + lq);
            xr[it] = *(const float4*)&x[(size_t)nh*C_IN + 4*l15];
          }
        }
        if (p + 2 < PPW) {
          int n2 = base + w*PPW + p + 2;  int nc2 = n2 < N_PTS ? n2 : N_PTS-1;
          idx_nn = neighbors[nc2*H_NB + (lane & 31)];
          c2x = points[nc2*3+0]; c2y = points[nc2*3+1]; c2z = points[nc2*3+2];
        }
        asm volatile("s_waitcnt lgkmcnt(0)" ::: "memory");
        ushort8 bbr[4];
        #pragma unroll
        for (int ct = 0; ct < 4; ++ct) {
          #pragma unroll
          for (int j = 0; j < 8; ++j)
            bbr[ct][j] = xgw[XG_PLANE*ct + XG_SUB*(2*lq + (j>>2)) + 16*(j&3) + l15];
        }
        f32x4 acc[4] = {{0,0,0,0},{0,0,0,0},{0,0,0,0},{0,0,0,0}};
        #pragma unroll
        for (int ct = 0; ct < 4; ++ct)
          acc[ct] = __builtin_amdgcn_mfma_f32_16x16x32_bf16(
              afrag, __builtin_bit_cast(bf16x8, bbr[ct]), acc[ct], 0, 0, 0);
        #pragma unroll
        for (int ct = 0; ct < 4; ++ct) {
          #pragma unroll
          for (int r = 0; r < 4; ++r) {
            int k = 4*lq + r;
            if (k < K_KP)
              wf_lds[mpt*WFS + k*C_IN + ((ct ^ lq)*16) + l15] = bfbits(acc[ct][r]);
          }
        }
        if (p + 1 < PPW) {
          pcx = pnx; pcy = pny; pcz = pnz;
          ccx = cnx; ccy = cny; ccz = cnz;
          idx_c = idx_n; idx_n = idx_nn;
          cnx = c2x; cny = c2y; cnz = c2z;
          if (p + 2 < PPW) {
            const float* pq = points + (size_t)idx_n*3;
            pnx = pq[0]; pny = pq[1]; pnz = pq[2];
          }
        }
      }
    }

    __syncthreads();
    const int wd = w;
    f32x4 b00{0,0,0,0}, b01{0,0,0,0}, b10{0,0,0,0}, b11{0,0,0,0};
    const unsigned short* arow0 = &wf_lds[l15*WFS];
    const unsigned short* arow1 = arow0 + 16*WFS;
    const unsigned short* wrow0 = Wt + (size_t)(wd*32 + l15)*KC + lq*8;
    const unsigned short* wrow1 = wrow0 + (size_t)16*KC;
    #pragma unroll 6
    for (int ks = 0; ks < KC/32; ++ks) {
      int aoff = (ks*32 + lq*8) ^ ((((ks >> 1) >> 2) & 3) << 4);
      bf16x8 a0 = ld_bf8(arow0 + aoff);
      bf16x8 a1 = ld_bf8(arow1 + aoff);
      bf16x8 w0 = ld_bf8(wrow0 + ks*32);
      bf16x8 w1 = ld_bf8(wrow1 + ks*32);
      b00 = __builtin_amdgcn_mfma_f32_16x16x32_bf16(a0, w0, b00, 0, 0, 0);
      b01 = __builtin_amdgcn_mfma_f32_16x16x32_bf16(a0, w1, b01, 0, 0, 0);
      b10 = __builtin_amdgcn_mfma_f32_16x16x32_bf16(a1, w0, b10, 0, 0, 0);
      b11 = __builtin_amdgcn_mfma_f32_16x16x32_bf16(a1, w1, b11, 0, 0, 0);
    }
    float s0 = 0.f, q0 = 0.f, s1 = 0.f, q1 = 0.f;
    const int dcol0 = wd*32 + l15;
    #pragma unroll
    for (int mi = 0; mi < 2; ++mi) {
      const f32x4 A0 = mi ? b10 : b00;
      const f32x4 A1 = mi ? b11 : b01;
      #pragma unroll
      for (int r = 0; r < 4; ++r) {
        int n = base + mi*16 + 4*lq + r;
        if (n < N_PTS) {
          float v0 = A0[r], v1 = A1[r];
          out_pre[(size_t)n*C_OUT + dcol0]      = v0;
          out_pre[(size_t)n*C_OUT + dcol0 + 16] = v1;
          s0 += v0; q0 += v0*v0;
          s1 += v1; q1 += v1*v1;
        }
      }
    }
    s0 += __shfl_xor(s0, 16); s0 += __shfl_xor(s0, 32);
    q0 += __shfl_xor(q0, 16); q0 += __shfl_xor(q0, 32);
    s1 += __shfl_xor(s1, 16); s1 += __shfl_xor(s1, 32);
    q1 += __shfl_xor(q1, 16); q1 += __shfl_xor(q1, 32);
    if (lane < 16) {
      sh_sum[wd*32 + lane]      = s0;
      sh_sum[wd*32 + 16 + lane] = s1;
      sh_sq [wd*32 + lane]      = q0;
      sh_sq [wd*32 + 16 + lane] = q1;
    }
    __syncthreads();
    if (tid < C_OUT) {
      atomicAdd(&stats[tid],         sh_sum[tid]);
      atomicAdd(&stats[C_OUT + tid], sh_sq[tid]);
    }
  }
}

// ---- split GEMM: 3-buffer pipeline, raw s_barrier + counted vmcnt (R19-proven) ----
__global__ __launch_bounds__(256, 2) void gemm_kernel(
    const unsigned short* __restrict__ wfg,
    const unsigned short* __restrict__ Wt,
    float* __restrict__ out_pre,
    float* __restrict__ stats)
{
  __shared__ __align__(16) unsigned short Abuf[3][64*64];
  __shared__ __align__(16) unsigned short Bbuf[3][128*64];
  __shared__ float sh_sum[2][C_OUT];
  __shared__ float sh_sq [2][C_OUT];

  const int tid  = threadIdx.x;
  const int w    = tid >> 6;
  const int lane = tid & 63;
  const int l15  = lane & 15;
  const int lq   = lane >> 4;
  const int wm   = w >> 1;
  const int wn   = w & 1;
  const int m0   = blockIdx.x * 64;

  const int r8 = lane >> 3;
  const int cs = (lane & 7) ^ r8;

  auto stage = [&](int b, int kt){
    const int k0 = kt * 64;
    #pragma unroll
    for (int q = 0; q < 2; ++q) {
      int row = w*16 + q*8;
      gload16(wfg + (size_t)(m0 + row + r8)*KC + k0 + cs*8, &Abuf[b][row*64]);
    }
    #pragma unroll
    for (int q = 0; q < 4; ++q) {
      int row = w*32 + q*8;
      gload16(Wt + (size_t)(row + r8)*KC + k0 + cs*8, &Bbuf[b][row*64]);
    }
  };

  stage(0, 0);
  stage(1, 1);

  f32x4 acc[2][4] = {};
  const int NT = KC / 64;   // 15
  for (int ks = 0; ks < NT; ++ks) {
    if (ks + 1 < NT) {
      asm volatile("s_waitcnt vmcnt(6)" ::: "memory");
    } else {
      asm volatile("s_waitcnt vmcnt(0)" ::: "memory");
    }
    __builtin_amdgcn_sched_barrier(0);
    __builtin_amdgcn_s_barrier();
    asm volatile("" ::: "memory");
    if (ks + 2 < NT) stage((ks + 2) % 3, ks + 2);

    const unsigned short* A = Abuf[ks % 3];
    const unsigned short* B = Bbuf[ks % 3];
    #pragma unroll
    for (int kk = 0; kk < 2; ++kk) {
      const int cA = kk*4 + lq;
      bf16x8 af[2], bfr[4];
      #pragma unroll
      for (int mf = 0; mf < 2; ++mf) {
        int r = wm*32 + mf*16 + l15;
        af[mf] = ld_bf8(A + r*64 + ((cA ^ (r & 7)) * 8));
      }
      #pragma unroll
      for (int nf = 0; nf < 4; ++nf) {
        int r = wn*64 + nf*16 + l15;
        bfr[nf] = ld_bf8(B + r*64 + ((cA ^ (r & 7)) * 8));
      }
      #pragma unroll
      for (int mf = 0; mf < 2; ++mf)
        #pragma unroll
        for (int nf = 0; nf < 4; ++nf)
          acc[mf][nf] = __builtin_amdgcn_mfma_f32_16x16x32_bf16(af[mf], bfr[nf], acc[mf][nf], 0, 0, 0);
    }
  }

  float ssum[4] = {0,0,0,0}, ssq[4] = {0,0,0,0};
  #pragma unroll
  for (int mf = 0; mf < 2; ++mf) {
    #pragma unroll
    for (int nf = 0; nf < 4; ++nf) {
      #pragma unroll
      for (int r = 0; r < 4; ++r) {
        int m = m0 + wm*32 + mf*16 + 4*lq + r;
        if (m < N_PTS) {
          float v = acc[mf][nf][r];
          out_pre[(size_t)m*C_OUT + wn*64 + nf*16 + l15] = v;
          ssum[nf] += v; ssq[nf] += v*v;
        }
      }
    }
  }
  #pragma unroll
  for (int nf = 0; nf < 4; ++nf) {
    ssum[nf] += __shfl_xor(ssum[nf], 16); ssum[nf] += __shfl_xor(ssum[nf], 32);
    ssq[nf]  += __shfl_xor(ssq[nf], 16);  ssq[nf]  += __shfl_xor(ssq[nf], 32);
  }
  if (lane < 16) {
    #pragma unroll
    for (int nf = 0; nf < 4; ++nf) {
      sh_sum[wm][wn*64 + nf*16 + lane] = ssum[nf];
      sh_sq [wm][wn*64 + nf*16 + lane] = ssq[nf];
    }
  }
  __syncthreads();
  if (tid < C_OUT) {
    atomicAdd(&stats[tid],         sh_sum[0][tid] + sh_sum[1][tid]);
    atomicAdd(&stats[C_OUT + tid], sh_sq[0][tid] + sh_sq[1][tid]);
  }
}

// ---- bn_lrelu with inline finalize ----
__global__ __launch_bounds__(256) void bn_lrelu_kernel(float* __restrict__ out,
                                                       const float* __restrict__ stats,
                                                       const float* __restrict__ gamma,
                                                       const float* __restrict__ beta){
  __shared__ float sc_s[C_OUT], sh_s[C_OUT];
  if (threadIdx.x < C_OUT) {
    int d = threadIdx.x;
    float mean = stats[d] * (1.f/N_PTS);
    float var  = stats[C_OUT+d] * (1.f/N_PTS) - mean*mean;
    var = var > 0.f ? var : 0.f;
    float inv = rsqrtf(var + BN_EPS);
    float sc  = inv * gamma[d];
    sc_s[d] = sc;
    sh_s[d] = beta[d] - mean * sc;
  }
  __syncthreads();
  const int total4 = N_PTS*C_OUT/4;
  const float4* scp = (const float4*)sc_s;
  const float4* shp = (const float4*)sh_s;
  float4* o4 = (float4*)out;
  for (int t = blockIdx.x*blockDim.x + threadIdx.x; t < total4; t += gridDim.x*blockDim.x) {
    int col4 = t & (C_OUT/4 - 1);
    float4 v = o4[t];
    float4 sc = scp[col4], sh = shp[col4];
    float y0 = v.x*sc.x + sh.x;
    float y1 = v.y*sc.y + sh.y;
    float y2 = v.z*sc.z + sh.z;
    float y3 = v.w*sc.w + sh.w;
    v.x = y0 > 0.f ? y0 : SLOPE*y0;
    v.y = y1 > 0.f ? y1 : SLOPE*y1;
    v.z = y2 > 0.f ? y2 : SLOPE*y2;
    v.w = y3 > 0.f ? y3 : SLOPE*y3;
    o4[t] = v;
  }
}

extern "C" void kernel_launch(void* const* d_in, const int* in_sizes, int n_in,
                              void* d_out, int out_size, void* d_ws, size_t ws_size,
                              hipStream_t stream) {
  const float* points    = (const float*)d_in[0];
  const float* x         = (const float*)d_in[1];
  const int*   neighbors = (const int*)d_in[2];
  const float* kpts      = (const float*)d_in[3];
  const float* weights   = (const float*)d_in[4];
  const float* gamma     = (const float*)d_in[5];
  const float* beta      = (const float*)d_in[6];
  float* out = (float*)d_out;
  float* ws  = (float*)d_ws;
  // ws layout: [0,1024) stats | [1024,2048) spare | [2048,+245760) Wt | then wfg (96 MB)
  unsigned short* Wt  = (unsigned short*)((char*)d_ws + 2048);
  unsigned short* wfg = (unsigned short*)((char*)d_ws + 2048 + 245760);
  // split-path xbf lives in d_out's front 6.4 MB (dead until gemm overwrites)
  unsigned short* xbf = (unsigned short*)d_out;
  const size_t need = 2048u + 245760u + (size_t)M_PAD*KC*2u;
  const bool split = (ws_size >= need);

  const int nblocks = (N_PTS + M_TILE - 1) / M_TILE;   // 1563
  if (split) {
    hipLaunchKernelGGL(prep_kernel, dim3(XPB + (KC/32)*(C_OUT/32)), dim3(256), 0, stream,
                       weights, x, Wt, xbf, ws);
    kpconv_core<true><<<dim3(nblocks), dim3(256), 0, stream>>>(
        points, x, xbf, neighbors, kpts, Wt, wfg, out, ws);
    gemm_kernel<<<dim3(M_PAD/64), dim3(256), 0, stream>>>(wfg, Wt, out, ws);
  } else {
    hipLaunchKernelGGL(prep_kernel, dim3(XPB + (KC/32)*(C_OUT/32)), dim3(256), 0, stream,
                       weights, x, Wt, xbf, ws);
    kpconv_core<false><<<dim3(nblocks), dim3(256), 0, stream>>>(
        points, x, xbf, neighbors, kpts, Wt, wfg, out, ws);
  }
  hipLaunchKernelGGL(bn_lrelu_kernel, dim3(2048), dim3(256), 0, stream, out, ws, gamma, beta);
}

// Round 23
// 115.748 us; speedup vs baseline: 1.4979x; 1.4979x over previous
//
#include <hip/hip_runtime.h>
#include <hip/hip_bf16.h>

#define N_PTS 50000
#define H_NB 32
#define K_KP 15
#define C_IN 64
#define C_OUT 128
#define KC 960           // K_KP * C_IN
#define M_PAD 50048      // padded wf rows (mult of 64)
#define M_TILE 32
#define PPW 8            // points per wave (4 waves/block)
#define WFS 968          // fused-path wf_lds row stride
#define XG_SUB 68        // fused-path xg strides
#define XG_PLANE 552
#define XG_WAVE (4*XG_PLANE)
#define BN_EPS 1e-5f
#define SLOPE 0.2f

typedef __attribute__((ext_vector_type(8))) __bf16 bf16x8;
typedef __attribute__((ext_vector_type(8))) unsigned short ushort8;
typedef __attribute__((ext_vector_type(4))) float f32x4;

__device__ __forceinline__ unsigned short bfbits(float f){
  return __builtin_bit_cast(unsigned short, (__bf16)f);
}
__device__ __forceinline__ bf16x8 ld_bf8(const unsigned short* p){
  return __builtin_bit_cast(bf16x8, *(const uint4*)p);
}
// async global->LDS DMA, 16B per lane; LDS dest = wave-uniform base + lane*16,
// global source address is PER-LANE (m173) -> usable for gathers.
__device__ __forceinline__ void gload16(const void* g, void* l){
  __builtin_amdgcn_global_load_lds(
      (__attribute__((address_space(1))) void*)(g),
      (__attribute__((address_space(3))) void*)(l), 16, 0, 0);
}

// ---- xprep: x f32 -> bf16 (RNE, identical numerics to staging-time conversion) ----
__global__ __launch_bounds__(256) void xprep_kernel(const float* __restrict__ x,
                                                    unsigned short* __restrict__ xbf){
  int t = blockIdx.x*blockDim.x + threadIdx.x;
  if (t < N_PTS*C_IN/8) {
    float4 a = ((const float4*)x)[2*t], b = ((const float4*)x)[2*t+1];
    ushort8 o;
    o[0]=bfbits(a.x); o[1]=bfbits(a.y); o[2]=bfbits(a.z); o[3]=bfbits(a.w);
    o[4]=bfbits(b.x); o[5]=bfbits(b.y); o[6]=bfbits(b.z); o[7]=bfbits(b.w);
    *(ushort8*)(xbf + 8*t) = o;
  }
}

// ---- prep: W[kc][d] f32 -> Wt[d][kc] bf16; block(0,0) zeros stats ----
__global__ __launch_bounds__(256) void prep_kernel(const float* __restrict__ W,
                                                   unsigned short* __restrict__ Wt,
                                                   float* __restrict__ stats){
  __shared__ float tile[32][33];
  if (blockIdx.x == 0 && blockIdx.y == 0 && threadIdx.x < 2*C_OUT)
    stats[threadIdx.x] = 0.f;
  const int kc0 = blockIdx.x * 32, d0 = blockIdx.y * 32;
  const int r = threadIdx.x >> 5, c = threadIdx.x & 31;
  #pragma unroll
  for (int rr = 0; rr < 4; ++rr) {
    int row = rr*8 + r;
    tile[row][c] = W[(size_t)(kc0+row)*C_OUT + d0 + c];
  }
  __syncthreads();
  #pragma unroll
  for (int rr = 0; rr < 4; ++rr) {
    int dr = rr*8 + r;
    Wt[(size_t)(d0+dr)*KC + kc0 + c] = bfbits(tile[c][dr]);
  }
}

// ---- core: Phase A (gather+influence MFMA). SPLIT: DMA-gathered bf16 x, wf->global.
//      !SPLIT: legacy fused (R7-verified). ----
// NOTE: SPLIT bound MUST stay 4 — bounds 5/6/8 (R22/R17/R14) all spill to scratch.
template<bool SPLIT>
__global__ __launch_bounds__(256, SPLIT ? 4 : 2) void kpconv_core(
    const float* __restrict__ points,
    const float* __restrict__ x,            // f32 x (fused path)
    const unsigned short* __restrict__ xbf, // bf16 x (split path)
    const int*   __restrict__ neighbors,
    const float* __restrict__ kpts,
    const unsigned short* __restrict__ Wt,
    unsigned short* __restrict__ wfg,
    float* __restrict__ out_pre,
    float* __restrict__ stats)
{
  // SPLIT: per-wave double buffer 2 x 2048 elems (4KB each). layout per buf:
  //   row h (64 elems), physical chunk pc holds logical chunk pc ^ (2*(h>>3))
  __shared__ __align__(16) unsigned short xg[SPLIT ? 4*4096 : 4*XG_WAVE];
  __shared__ unsigned short wf_lds[SPLIT ? 8 : M_TILE*WFS];
  __shared__ float sh_sum[SPLIT ? 1 : C_OUT];
  __shared__ float sh_sq [SPLIT ? 1 : C_OUT];

  const int tid  = threadIdx.x;
  const int w    = tid >> 6;
  const int lane = tid & 63;
  const int l15  = lane & 15;
  const int lq   = lane >> 4;
  const int base = blockIdx.x * M_TILE;

  float kqx, kqy, kqz;
  if (l15 < K_KP) { kqx = kpts[l15*3+0]; kqy = kpts[l15*3+1]; kqz = kpts[l15*3+2]; }
  else            { kqx = 1e3f; kqy = 0.f; kqz = 0.f; }

  if constexpr (SPLIT) {
    // ------------- split Phase A: gather via global_load_lds, double-buffered -------------
    unsigned short* xb0 = &xg[w * 4096];
    unsigned short* xb1 = xb0 + 2048;

    const int r8 = lane >> 3;       // gather row-within-8
    const int pc = lane & 7;        // physical chunk this lane fills

    auto dma_point = [&](unsigned short* buf, int idx){
      #pragma unroll
      for (int it = 0; it < 4; ++it) {
        int nh = __shfl(idx, 8*it + r8);
        // pre-swizzled source: physical chunk pc holds logical chunk pc ^ (2*it)
        const unsigned short* src = xbf + (size_t)nh*C_IN + ((pc ^ (2*it)) * 8);
        gload16(src, buf + it*512);
      }
    };

    int   idx_c, idx_n = 0, idx_nn = 0;
    float pcx, pcy, pcz, pnx = 0, pny = 0, pnz = 0;
    float ccx, ccy, ccz, cnx = 0, cny = 0, cnz = 0, c2x = 0, c2y = 0, c2z = 0;
    {
      int n0 = base + w*PPW;  int nc0 = n0 < N_PTS ? n0 : N_PTS-1;
      idx_c = neighbors[nc0*H_NB + (lane & 31)];
      ccx = points[nc0*3+0]; ccy = points[nc0*3+1]; ccz = points[nc0*3+2];
      const float* pp = points + (size_t)idx_c*3;
      pcx = pp[0]; pcy = pp[1]; pcz = pp[2];
      int n1 = n0 + 1;  int nc1 = n1 < N_PTS ? n1 : N_PTS-1;
      idx_n = neighbors[nc1*H_NB + (lane & 31)];
      cnx = points[nc1*3+0]; cny = points[nc1*3+1]; cnz = points[nc1*3+2];
      const float* pq = points + (size_t)idx_n*3;
      pnx = pq[0]; pny = pq[1]; pnz = pq[2];
      dma_point(xb0, idx_c);   // point 0
      dma_point(xb1, idx_n);   // point 1
    }

    unsigned short* cur = xb0;
    unsigned short* nxt = xb1;

    #pragma unroll 1
    for (int p = 0; p < PPW; ++p) {
      // influence A-frag: lane holds infl(kernel-pt m=l15, h = lq*8+j)
      float rx = pcx - ccx, ry = pcy - ccy, rz = pcz - ccz;
      bf16x8 afrag;
      #pragma unroll
      for (int j = 0; j < 8; ++j) {
        int h = (lq << 3) + j;
        float dx = __shfl(rx, h) - kqx;
        float dy = __shfl(ry, h) - kqy;
        float dz = __shfl(rz, h) - kqz;
        float f  = 1.f - sqrtf(dx*dx + dy*dy + dz*dz);
        afrag[j] = (__bf16)(f > 0.f ? f : 0.f);
      }

      // early-issue next-next point's idx/center
      if (p + 2 < PPW) {
        int n2 = base + w*PPW + p + 2;  int nc2 = n2 < N_PTS ? n2 : N_PTS-1;
        idx_nn = neighbors[nc2*H_NB + (lane & 31)];
        c2x = points[nc2*3+0]; c2y = points[nc2*3+1]; c2z = points[nc2*3+2];
      }

      // wait for this point's DMA only; DMA(p+1)'s 4 ops (strictly younger) stay in flight
      if (p + 1 < PPW) { asm volatile("s_waitcnt vmcnt(4)" ::: "memory"); }
      else             { asm volatile("s_waitcnt vmcnt(0)" ::: "memory"); }
      __builtin_amdgcn_sched_barrier(0);

      // B-frag reads: logical (h = lq*8+j, elem ct*16+l15); physical chunk = lc ^ (2*lq)
      // -> banks fully spread (conflict-free, measured 400K), 2-way same-dword broadcast
      f32x4 acc[4] = {{0,0,0,0},{0,0,0,0},{0,0,0,0},{0,0,0,0}};
      #pragma unroll
      for (int ct = 0; ct < 4; ++ct) {
        ushort8 b;
        const int pcr = ((2*ct + (l15 >> 3)) ^ (2*lq)) * 8 + (l15 & 7);
        #pragma unroll
        for (int j = 0; j < 8; ++j)
          b[j] = cur[lq*512 + j*64 + pcr];
        acc[ct] = __builtin_amdgcn_mfma_f32_16x16x32_bf16(
            afrag, __builtin_bit_cast(bf16x8, b), acc[ct], 0, 0, 0);
      }

      // bounce acc -> cur (k-stride 72), then coalesced 16B stores to wfg
      const int n_out = base + w*PPW + p;
      #pragma unroll
      for (int ct = 0; ct < 4; ++ct) {
        #pragma unroll
        for (int r = 0; r < 4; ++r) {
          int k = 4*lq + r;
          if (k < K_KP)
            cur[72*k + ct*16 + l15] = bfbits(acc[ct][r]);
        }
      }
      asm volatile("s_waitcnt lgkmcnt(0)" ::: "memory");
      if (n_out < N_PTS) {
        uint4 c0 = *(const uint4*)(cur + 72*(lane>>3) + 8*(lane&7));
        *(uint4*)(wfg + (size_t)n_out*KC + lane*8) = c0;
        if (lane < 56) {
          int ch = 64 + lane;
          uint4 c1 = *(const uint4*)(cur + 72*(ch>>3) + 8*(ch&7));
          *(uint4*)(wfg + (size_t)n_out*KC + ch*8) = c1;
        }
      }
      asm volatile("s_waitcnt lgkmcnt(0)" ::: "memory");

      // rotate pipeline; prefetch npos for new "next"; issue DMA for p+2 into cur
      if (p + 1 < PPW) {
        pcx = pnx; pcy = pny; pcz = pnz;
        ccx = cnx; ccy = cny; ccz = cnz;
        idx_c = idx_n; idx_n = idx_nn;
        cnx = c2x; cny = c2y; cnz = c2z;
        if (p + 2 < PPW) {
          const float* pq = points + (size_t)idx_n*3;
          pnx = pq[0]; pny = pq[1]; pnz = pq[2];
          dma_point(cur, idx_n);          // point p+2 reuses the buffer just drained
        }
        unsigned short* t = cur; cur = nxt; nxt = t;
      }
    }
  } else {
    // ------------- legacy fused path (R7-verified), f32 x -------------
    unsigned short* xgw = &xg[w * XG_WAVE];
    {
      int   idx_c, idx_n = 0, idx_nn = 0;
      float pcx, pcy, pcz, pnx = 0, pny = 0, pnz = 0;
      float ccx, ccy, ccz, cnx = 0, cny = 0, cnz = 0, c2x = 0, c2y = 0, c2z = 0;
      float4 xr[8];
      {
        int n0 = base + w*PPW;  int nc0 = n0 < N_PTS ? n0 : N_PTS-1;
        idx_c = neighbors[nc0*H_NB + (lane & 31)];
        ccx = points[nc0*3+0]; ccy = points[nc0*3+1]; ccz = points[nc0*3+2];
        const float* pp = points + (size_t)idx_c*3;
        pcx = pp[0]; pcy = pp[1]; pcz = pp[2];
        #pragma unroll
        for (int it = 0; it < 8; ++it) {
          int nh = __shfl(idx_c, 4*it + lq);
          xr[it] = *(const float4*)&x[(size_t)nh*C_IN + 4*l15];
        }
        int n1 = n0 + 1;  int nc1 = n1 < N_PTS ? n1 : N_PTS-1;
        idx_n = neighbors[nc1*H_NB + (lane & 31)];
        cnx = points[nc1*3+0]; cny = points[nc1*3+1]; cnz = points[nc1*3+2];
        const float* pq = points + (size_t)idx_n*3;
        pnx = pq[0]; pny = pq[1]; pnz = pq[2];
      }

      #pragma unroll 1
      for (int p = 0; p < PPW; ++p) {
        const int mpt = w*PPW + p;
        float rx = pcx - ccx, ry = pcy - ccy, rz = pcz - ccz;
        bf16x8 afrag;
        #pragma unroll
        for (int j = 0; j < 8; ++j) {
          int h = (lq << 3) + j;
          float dx = __shfl(rx, h) - kqx;
          float dy = __shfl(ry, h) - kqy;
          float dz = __shfl(rz, h) - kqz;
          float f  = 1.f - sqrtf(dx*dx + dy*dy + dz*dz);
          afrag[j] = (__bf16)(f > 0.f ? f : 0.f);
        }
        #pragma unroll
        for (int it = 0; it < 8; ++it) {
          float4 v = xr[it];
          unsigned lo = ((unsigned)bfbits(v.y) << 16) | bfbits(v.x);
          unsigned hi = ((unsigned)bfbits(v.w) << 16) | bfbits(v.z);
          int ei = XG_PLANE*(l15 >> 2) + XG_SUB*it + 16*lq + 4*(l15 & 3);
          uint2 val; val.x = lo; val.y = hi;
          *(uint2*)(xgw + ei) = val;
        }
        if (p + 1 < PPW) {
          #pragma unroll
          for (int it = 0; it < 8; ++it) {
            int nh = __shfl(idx_n, 4*it + lq);
            xr[it] = *(const float4*)&x[(size_t)nh*C_IN + 4*l15];
          }
        }
        if (p + 2 < PPW) {
          int n2 = base + w*PPW + p + 2;  int nc2 = n2 < N_PTS ? n2 : N_PTS-1;
          idx_nn = neighbors[nc2*H_NB + (lane & 31)];
          c2x = points[nc2*3+0]; c2y = points[nc2*3+1]; c2z = points[nc2*3+2];
        }
        asm volatile("s_waitcnt lgkmcnt(0)" ::: "memory");
        ushort8 bbr[4];
        #pragma unroll
        for (int ct = 0; ct < 4; ++ct) {
          #pragma unroll
          for (int j = 0; j < 8; ++j)
            bbr[ct][j] = xgw[XG_PLANE*ct + XG_SUB*(2*lq + (j>>2)) + 16*(j&3) + l15];
        }
        f32x4 acc[4] = {{0,0,0,0},{0,0,0,0},{0,0,0,0},{0,0,0,0}};
        #pragma unroll
        for (int ct = 0; ct < 4; ++ct)
          acc[ct] = __builtin_amdgcn_mfma_f32_16x16x32_bf16(
              afrag, __builtin_bit_cast(bf16x8, bbr[ct]), acc[ct], 0, 0, 0);
        #pragma unroll
        for (int ct = 0; ct < 4; ++ct) {
          #pragma unroll
          for (int r = 0; r < 4; ++r) {
            int k = 4*lq + r;
            if (k < K_KP)
              wf_lds[mpt*WFS + k*C_IN + ((ct ^ lq)*16) + l15] = bfbits(acc[ct][r]);
          }
        }
        if (p + 1 < PPW) {
          pcx = pnx; pcy = pny; pcz = pnz;
          ccx = cnx; ccy = cny; ccz = cnz;
          idx_c = idx_n; idx_n = idx_nn;
          cnx = c2x; cny = c2y; cnz = c2z;
          if (p + 2 < PPW) {
            const float* pq = points + (size_t)idx_n*3;
            pnx = pq[0]; pny = pq[1]; pnz = pq[2];
          }
        }
      }
    }

    __syncthreads();
    const int wd = w;
    f32x4 b00{0,0,0,0}, b01{0,0,0,0}, b10{0,0,0,0}, b11{0,0,0,0};
    const unsigned short* arow0 = &wf_lds[l15*WFS];
    const unsigned short* arow1 = arow0 + 16*WFS;
    const unsigned short* wrow0 = Wt + (size_t)(wd*32 + l15)*KC + lq*8;
    const unsigned short* wrow1 = wrow0 + (size_t)16*KC;
    #pragma unroll 6
    for (int ks = 0; ks < KC/32; ++ks) {
      int aoff = (ks*32 + lq*8) ^ ((((ks >> 1) >> 2) & 3) << 4);
      bf16x8 a0 = ld_bf8(arow0 + aoff);
      bf16x8 a1 = ld_bf8(arow1 + aoff);
      bf16x8 w0 = ld_bf8(wrow0 + ks*32);
      bf16x8 w1 = ld_bf8(wrow1 + ks*32);
      b00 = __builtin_amdgcn_mfma_f32_16x16x32_bf16(a0, w0, b00, 0, 0, 0);
      b01 = __builtin_amdgcn_mfma_f32_16x16x32_bf16(a0, w1, b01, 0, 0, 0);
      b10 = __builtin_amdgcn_mfma_f32_16x16x32_bf16(a1, w0, b10, 0, 0, 0);
      b11 = __builtin_amdgcn_mfma_f32_16x16x32_bf16(a1, w1, b11, 0, 0, 0);
    }
    float s0 = 0.f, q0 = 0.f, s1 = 0.f, q1 = 0.f;
    const int dcol0 = wd*32 + l15;
    #pragma unroll
    for (int mi = 0; mi < 2; ++mi) {
      const f32x4 A0 = mi ? b10 : b00;
      const f32x4 A1 = mi ? b11 : b01;
      #pragma unroll
      for (int r = 0; r < 4; ++r) {
        int n = base + mi*16 + 4*lq + r;
        if (n < N_PTS) {
          float v0 = A0[r], v1 = A1[r];
          out_pre[(size_t)n*C_OUT + dcol0]      = v0;
          out_pre[(size_t)n*C_OUT + dcol0 + 16] = v1;
          s0 += v0; q0 += v0*v0;
          s1 += v1; q1 += v1*v1;
        }
      }
    }
    s0 += __shfl_xor(s0, 16); s0 += __shfl_xor(s0, 32);
    q0 += __shfl_xor(q0, 16); q0 += __shfl_xor(q0, 32);
    s1 += __shfl_xor(s1, 16); s1 += __shfl_xor(s1, 32);
    q1 += __shfl_xor(q1, 16); q1 += __shfl_xor(q1, 32);
    if (lane < 16) {
      sh_sum[wd*32 + lane]      = s0;
      sh_sum[wd*32 + 16 + lane] = s1;
      sh_sq [wd*32 + lane]      = q0;
      sh_sq [wd*32 + 16 + lane] = q1;
    }
    __syncthreads();
    if (tid < C_OUT) {
      atomicAdd(&stats[tid],         sh_sum[tid]);
      atomicAdd(&stats[C_OUT + tid], sh_sq[tid]);
    }
  }
}

// ---- split GEMM: 3-buffer pipeline, raw s_barrier + counted vmcnt (R19-proven) ----
__global__ __launch_bounds__(256, 2) void gemm_kernel(
    const unsigned short* __restrict__ wfg,
    const unsigned short* __restrict__ Wt,
    float* __restrict__ out_pre,
    float* __restrict__ stats)
{
  __shared__ __align__(16) unsigned short Abuf[3][64*64];
  __shared__ __align__(16) unsigned short Bbuf[3][128*64];
  __shared__ float sh_sum[2][C_OUT];
  __shared__ float sh_sq [2][C_OUT];

  const int tid  = threadIdx.x;
  const int w    = tid >> 6;
  const int lane = tid & 63;
  const int l15  = lane & 15;
  const int lq   = lane >> 4;
  const int wm   = w >> 1;
  const int wn   = w & 1;
  const int m0   = blockIdx.x * 64;

  const int r8 = lane >> 3;
  const int cs = (lane & 7) ^ r8;

  auto stage = [&](int b, int kt){
    const int k0 = kt * 64;
    #pragma unroll
    for (int q = 0; q < 2; ++q) {
      int row = w*16 + q*8;
      gload16(wfg + (size_t)(m0 + row + r8)*KC + k0 + cs*8, &Abuf[b][row*64]);
    }
    #pragma unroll
    for (int q = 0; q < 4; ++q) {
      int row = w*32 + q*8;
      gload16(Wt + (size_t)(row + r8)*KC + k0 + cs*8, &Bbuf[b][row*64]);
    }
  };

  stage(0, 0);
  stage(1, 1);

  f32x4 acc[2][4] = {};
  const int NT = KC / 64;   // 15
  for (int ks = 0; ks < NT; ++ks) {
    if (ks + 1 < NT) {
      asm volatile("s_waitcnt vmcnt(6)" ::: "memory");
    } else {
      asm volatile("s_waitcnt vmcnt(0)" ::: "memory");
    }
    __builtin_amdgcn_sched_barrier(0);
    __builtin_amdgcn_s_barrier();
    asm volatile("" ::: "memory");
    if (ks + 2 < NT) stage((ks + 2) % 3, ks + 2);

    const unsigned short* A = Abuf[ks % 3];
    const unsigned short* B = Bbuf[ks % 3];
    #pragma unroll
    for (int kk = 0; kk < 2; ++kk) {
      const int cA = kk*4 + lq;
      bf16x8 af[2], bfr[4];
      #pragma unroll
      for (int mf = 0; mf < 2; ++mf) {
        int r = wm*32 + mf*16 + l15;
        af[mf] = ld_bf8(A + r*64 + ((cA ^ (r & 7)) * 8));
      }
      #pragma unroll
      for (int nf = 0; nf < 4; ++nf) {
        int r = wn*64 + nf*16 + l15;
        bfr[nf] = ld_bf8(B + r*64 + ((cA ^ (r & 7)) * 8));
      }
      #pragma unroll
      for (int mf = 0; mf < 2; ++mf)
        #pragma unroll
        for (int nf = 0; nf < 4; ++nf)
          acc[mf][nf] = __builtin_amdgcn_mfma_f32_16x16x32_bf16(af[mf], bfr[nf], acc[mf][nf], 0, 0, 0);
    }
  }

  float ssum[4] = {0,0,0,0}, ssq[4] = {0,0,0,0};
  #pragma unroll
  for (int mf = 0; mf < 2; ++mf) {
    #pragma unroll
    for (int nf = 0; nf < 4; ++nf) {
      #pragma unroll
      for (int r = 0; r < 4; ++r) {
        int m = m0 + wm*32 + mf*16 + 4*lq + r;
        if (m < N_PTS) {
          float v = acc[mf][nf][r];
          out_pre[(size_t)m*C_OUT + wn*64 + nf*16 + l15] = v;
          ssum[nf] += v; ssq[nf] += v*v;
        }
      }
    }
  }
  #pragma unroll
  for (int nf = 0; nf < 4; ++nf) {
    ssum[nf] += __shfl_xor(ssum[nf], 16); ssum[nf] += __shfl_xor(ssum[nf], 32);
    ssq[nf]  += __shfl_xor(ssq[nf], 16);  ssq[nf]  += __shfl_xor(ssq[nf], 32);
  }
  if (lane < 16) {
    #pragma unroll
    for (int nf = 0; nf < 4; ++nf) {
      sh_sum[wm][wn*64 + nf*16 + lane] = ssum[nf];
      sh_sq [wm][wn*64 + nf*16 + lane] = ssq[nf];
    }
  }
  __syncthreads();
  if (tid < C_OUT) {
    atomicAdd(&stats[tid],         sh_sum[0][tid] + sh_sum[1][tid]);
    atomicAdd(&stats[C_OUT + tid], sh_sq[0][tid] + sh_sq[1][tid]);
  }
}

// ---- bn_lrelu with inline finalize ----
__global__ __launch_bounds__(256) void bn_lrelu_kernel(float* __restrict__ out,
                                                       const float* __restrict__ stats,
                                                       const float* __restrict__ gamma,
                                                       const float* __restrict__ beta){
  __shared__ float sc_s[C_OUT], sh_s[C_OUT];
  if (threadIdx.x < C_OUT) {
    int d = threadIdx.x;
    float mean = stats[d] * (1.f/N_PTS);
    float var  = stats[C_OUT+d] * (1.f/N_PTS) - mean*mean;
    var = var > 0.f ? var : 0.f;
    float inv = rsqrtf(var + BN_EPS);
    float sc  = inv * gamma[d];
    sc_s[d] = sc;
    sh_s[d] = beta[d] - mean * sc;
  }
  __syncthreads();
  const int total4 = N_PTS*C_OUT/4;
  const float4* scp = (const float4*)sc_s;
  const float4* shp = (const float4*)sh_s;
  float4* o4 = (float4*)out;
  for (int t = blockIdx.x*blockDim.x + threadIdx.x; t < total4; t += gridDim.x*blockDim.x) {
    int col4 = t & (C_OUT/4 - 1);
    float4 v = o4[t];
    float4 sc = scp[col4], sh = shp[col4];
    float y0 = v.x*sc.x + sh.x;
    float y1 = v.y*sc.y + sh.y;
    float y2 = v.z*sc.z + sh.z;
    float y3 = v.w*sc.w + sh.w;
    v.x = y0 > 0.f ? y0 : SLOPE*y0;
    v.y = y1 > 0.f ? y1 : SLOPE*y1;
    v.z = y2 > 0.f ? y2 : SLOPE*y2;
    v.w = y3 > 0.f ? y3 : SLOPE*y3;
    o4[t] = v;
  }
}

extern "C" void kernel_launch(void* const* d_in, const int* in_sizes, int n_in,
                              void* d_out, int out_size, void* d_ws, size_t ws_size,
                              hipStream_t stream) {
  const float* points    = (const float*)d_in[0];
  const float* x         = (const float*)d_in[1];
  const int*   neighbors = (const int*)d_in[2];
  const float* kpts      = (const float*)d_in[3];
  const float* weights   = (const float*)d_in[4];
  const float* gamma     = (const float*)d_in[5];
  const float* beta      = (const float*)d_in[6];
  float* out = (float*)d_out;
  float* ws  = (float*)d_ws;
  // ws layout: [0,1024) stats | [1024,2048) spare | [2048,+245760) Wt | then wfg (96 MB)
  unsigned short* Wt  = (unsigned short*)((char*)d_ws + 2048);
  unsigned short* wfg = (unsigned short*)((char*)d_ws + 2048 + 245760);
  // split-path xbf lives in d_out's front 6.4 MB (dead until gemm overwrites)
  unsigned short* xbf = (unsigned short*)d_out;
  const size_t need = 2048u + 245760u + (size_t)M_PAD*KC*2u;
  const bool split = (ws_size >= need);

  hipLaunchKernelGGL(prep_kernel, dim3(KC/32, C_OUT/32), dim3(256), 0, stream,
                     weights, Wt, ws);
  const int nblocks = (N_PTS + M_TILE - 1) / M_TILE;   // 1563
  if (split) {
    hipLaunchKernelGGL(xprep_kernel, dim3((N_PTS*C_IN/8 + 255)/256), dim3(256), 0, stream,
                       x, xbf);
    kpconv_core<true><<<dim3(nblocks), dim3(256), 0, stream>>>(
        points, x, xbf, neighbors, kpts, Wt, wfg, out, ws);
    gemm_kernel<<<dim3(M_PAD/64), dim3(256), 0, stream>>>(wfg, Wt, out, ws);
  } else {
    kpconv_core<false><<<dim3(nblocks), dim3(256), 0, stream>>>(
        points, x, xbf, neighbors, kpts, Wt, wfg, out, ws);
  }
  hipLaunchKernelGGL(bn_lrelu_kernel, dim3(2048), dim3(256), 0, stream, out, ws, gamma, beta);
}

// Round 24
// 111.501 us; speedup vs baseline: 1.5549x; 1.0381x over previous
//
#include <hip/hip_runtime.h>
#include <hip/hip_bf16.h>

#define N_PTS 50000
#define H_NB 32
#define K_KP 15
#define C_IN 64
#define C_OUT 128
#define KC 960           // K_KP * C_IN
#define M_PAD 50048      // padded wf rows (mult of 64)
#define M_TILE 32
#define PPW 8            // points per wave (4 waves/block)
#define WFS 968          // fused-path wf_lds row stride
#define XG_SUB 68        // fused-path xg strides
#define XG_PLANE 552
#define XG_WAVE (4*XG_PLANE)
#define BN_EPS 1e-5f
#define SLOPE 0.2f

typedef __attribute__((ext_vector_type(8))) __bf16 bf16x8;
typedef __attribute__((ext_vector_type(8))) unsigned short ushort8;
typedef __attribute__((ext_vector_type(4))) float f32x4;

__device__ __forceinline__ unsigned short bfbits(float f){
  return __builtin_bit_cast(unsigned short, (__bf16)f);
}
__device__ __forceinline__ bf16x8 ld_bf8(const unsigned short* p){
  return __builtin_bit_cast(bf16x8, *(const uint4*)p);
}
// async global->LDS DMA, 16B per lane; global source address is PER-LANE (gather-capable)
__device__ __forceinline__ void gload16(const void* g, void* l){
  __builtin_amdgcn_global_load_lds(
      (__attribute__((address_space(1))) void*)(g),
      (__attribute__((address_space(3))) void*)(l), 16, 0, 0);
}

// ---- xprep: x f32 -> bf16 (RNE, identical numerics to staging-time conversion) ----
__global__ __launch_bounds__(256) void xprep_kernel(const float* __restrict__ x,
                                                    unsigned short* __restrict__ xbf){
  int t = blockIdx.x*blockDim.x + threadIdx.x;
  if (t < N_PTS*C_IN/8) {
    float4 a = ((const float4*)x)[2*t], b = ((const float4*)x)[2*t+1];
    ushort8 o;
    o[0]=bfbits(a.x); o[1]=bfbits(a.y); o[2]=bfbits(a.z); o[3]=bfbits(a.w);
    o[4]=bfbits(b.x); o[5]=bfbits(b.y); o[6]=bfbits(b.z); o[7]=bfbits(b.w);
    *(ushort8*)(xbf + 8*t) = o;
  }
}

// ---- prep: W[kc][d] f32 -> Wt[d][kc] bf16; block(0,0) zeros stats ----
__global__ __launch_bounds__(256) void prep_kernel(const float* __restrict__ W,
                                                   unsigned short* __restrict__ Wt,
                                                   float* __restrict__ stats){
  __shared__ float tile[32][33];
  if (blockIdx.x == 0 && blockIdx.y == 0 && threadIdx.x < 2*C_OUT)
    stats[threadIdx.x] = 0.f;
  const int kc0 = blockIdx.x * 32, d0 = blockIdx.y * 32;
  const int r = threadIdx.x >> 5, c = threadIdx.x & 31;
  #pragma unroll
  for (int rr = 0; rr < 4; ++rr) {
    int row = rr*8 + r;
    tile[row][c] = W[(size_t)(kc0+row)*C_OUT + d0 + c];
  }
  __syncthreads();
  #pragma unroll
  for (int rr = 0; rr < 4; ++rr) {
    int dr = rr*8 + r;
    Wt[(size_t)(d0+dr)*KC + kc0 + c] = bfbits(tile[c][dr]);
  }
}

// ---- core: Phase A. SPLIT: DMA-gathered bf16 x, statically-counted vmcnt pipeline.
//      !SPLIT: legacy fused (R7-verified). ----
// NOTE: SPLIT bound MUST stay 4 — bounds 5/6/8 (R22/R17/R14) all spill to scratch.
template<bool SPLIT>
__global__ __launch_bounds__(256, SPLIT ? 4 : 2) void kpconv_core(
    const float* __restrict__ points,
    const float* __restrict__ x,            // f32 x (fused path)
    const unsigned short* __restrict__ xbf, // bf16 x (split path)
    const int*   __restrict__ neighbors,
    const float* __restrict__ kpts,
    const unsigned short* __restrict__ Wt,
    unsigned short* __restrict__ wfg,
    float* __restrict__ out_pre,
    float* __restrict__ stats)
{
  __shared__ __align__(16) unsigned short xg[SPLIT ? 4*4096 : 4*XG_WAVE];
  __shared__ unsigned short wf_lds[SPLIT ? 8 : M_TILE*WFS];
  __shared__ float sh_sum[SPLIT ? 1 : C_OUT];
  __shared__ float sh_sq [SPLIT ? 1 : C_OUT];

  const int tid  = threadIdx.x;
  const int w    = tid >> 6;
  const int lane = tid & 63;
  const int l15  = lane & 15;
  const int lq   = lane >> 4;
  const int base = blockIdx.x * M_TILE;

  float kqx, kqy, kqz;
  if (l15 < K_KP) { kqx = kpts[l15*3+0]; kqy = kpts[l15*3+1]; kqz = kpts[l15*3+2]; }
  else            { kqx = 1e3f; kqy = 0.f; kqz = 0.f; }

  if constexpr (SPLIT) {
    // per-wave double buffer 2 x 2048 elems; row h, phys chunk pc = logical pc^(2*(h>>3))
    unsigned short* xb0 = &xg[w * 4096];
    unsigned short* xb1 = xb0 + 2048;
    const int r8 = lane >> 3;
    const int pc = lane & 7;

    auto dma_point = [&](unsigned short* buf, int idx){
      #pragma unroll
      for (int it = 0; it < 4; ++it) {
        int nh = __shfl(idx, 8*it + r8);
        const unsigned short* src = xbf + (size_t)nh*C_IN + ((pc ^ (2*it)) * 8);
        gload16(src, buf + it*512);
      }
    };

    // ---- prologue: hoist all idx/centers (static arrays under full unroll) ----
    int   idxs[PPW];
    float cx[PPW], cy[PPW], cz[PPW];
    #pragma unroll
    for (int i = 0; i < PPW; ++i) {
      int ni = base + w*PPW + i;
      int nc = ni < N_PTS ? ni : N_PTS-1;
      idxs[i] = neighbors[nc*H_NB + (lane & 31)];
      cx[i] = points[nc*3+0]; cy[i] = points[nc*3+1]; cz[i] = points[nc*3+2];
    }
    float p0x, p0y, p0z, p1x, p1y, p1z;
    { const float* pp = points + (size_t)idxs[0]*3; p0x = pp[0]; p0y = pp[1]; p0z = pp[2]; }
    { const float* pq = points + (size_t)idxs[1]*3; p1x = pq[0]; p1y = pq[1]; p1z = pq[2]; }
    __builtin_amdgcn_sched_barrier(0);
    dma_point(xb0, idxs[0]);
    dma_point(xb1, idxs[1]);
    __builtin_amdgcn_sched_barrier(0);

    #pragma unroll
    for (int p = 0; p < PPW; ++p) {
      unsigned short* cur = (p & 1) ? xb1 : xb0;

      // influence A-frag from npos(p) and hoisted center[p] (VALU only)
      float rx = p0x - cx[p], ry = p0y - cy[p], rz = p0z - cz[p];
      bf16x8 afrag;
      #pragma unroll
      for (int j = 0; j < 8; ++j) {
        int h = (lq << 3) + j;
        float dx = __shfl(rx, h) - kqx;
        float dy = __shfl(ry, h) - kqy;
        float dz = __shfl(rz, h) - kqz;
        float f  = 1.f - sqrtf(dx*dx + dy*dy + dz*dz);
        afrag[j] = (__bf16)(f > 0.f ? f : 0.f);
      }

      // statically-counted wait: younger-than-DMA(p) = stores(2)+npos(>=1)+DMA(p+1)(4) = 7 min
      if (p == 0)            { asm volatile("s_waitcnt vmcnt(4)" ::: "memory"); }
      else if (p == PPW - 1) { asm volatile("s_waitcnt vmcnt(0)" ::: "memory"); }
      else                   { asm volatile("s_waitcnt vmcnt(7)" ::: "memory"); }
      __builtin_amdgcn_sched_barrier(0);

      // B-frag reads (conflict-free, measured 400K) + MFMA
      f32x4 acc[4] = {{0,0,0,0},{0,0,0,0},{0,0,0,0},{0,0,0,0}};
      #pragma unroll
      for (int ct = 0; ct < 4; ++ct) {
        ushort8 b;
        const int pcr = ((2*ct + (l15 >> 3)) ^ (2*lq)) * 8 + (l15 & 7);
        #pragma unroll
        for (int j = 0; j < 8; ++j)
          b[j] = cur[lq*512 + j*64 + pcr];
        acc[ct] = __builtin_amdgcn_mfma_f32_16x16x32_bf16(
            afrag, __builtin_bit_cast(bf16x8, b), acc[ct], 0, 0, 0);
      }

      // bounce acc -> cur (k-stride 72), then UNCONDITIONAL coalesced stores (rows < M_PAD)
      const int n_out = base + w*PPW + p;   // <= 50015 < M_PAD; rows >= N_PTS masked downstream
      #pragma unroll
      for (int ct = 0; ct < 4; ++ct) {
        #pragma unroll
        for (int r = 0; r < 4; ++r) {
          int k = 4*lq + r;
          if (k < K_KP)
            cur[72*k + ct*16 + l15] = bfbits(acc[ct][r]);
        }
      }
      asm volatile("s_waitcnt lgkmcnt(0)" ::: "memory");
      {
        uint4 c0 = *(const uint4*)(cur + 72*(lane>>3) + 8*(lane&7));
        *(uint4*)(wfg + (size_t)n_out*KC + lane*8) = c0;
        if (lane < 56) {
          int ch = 64 + lane;
          uint4 c1 = *(const uint4*)(cur + 72*(ch>>3) + 8*(ch&7));
          *(uint4*)(wfg + (size_t)n_out*KC + ch*8) = c1;
        }
      }
      asm volatile("s_waitcnt lgkmcnt(0)" ::: "memory");
      __builtin_amdgcn_sched_barrier(0);

      // rotation: npos(p+2) then DMA(p+2) into cur (order pinned)
      p0x = p1x; p0y = p1y; p0z = p1z;
      if (p + 2 < PPW) {
        const float* pq = points + (size_t)idxs[p+2]*3;
        p1x = pq[0]; p1y = pq[1]; p1z = pq[2];
        __builtin_amdgcn_sched_barrier(0);
        dma_point(cur, idxs[p+2]);
        __builtin_amdgcn_sched_barrier(0);
      }
    }
  } else {
    // ------------- legacy fused path (R7-verified), f32 x -------------
    unsigned short* xgw = &xg[w * XG_WAVE];
    {
      int   idx_c, idx_n = 0, idx_nn = 0;
      float pcx, pcy, pcz, pnx = 0, pny = 0, pnz = 0;
      float ccx, ccy, ccz, cnx = 0, cny = 0, cnz = 0, c2x = 0, c2y = 0, c2z = 0;
      float4 xr[8];
      {
        int n0 = base + w*PPW;  int nc0 = n0 < N_PTS ? n0 : N_PTS-1;
        idx_c = neighbors[nc0*H_NB + (lane & 31)];
        ccx = points[nc0*3+0]; ccy = points[nc0*3+1]; ccz = points[nc0*3+2];
        const float* pp = points + (size_t)idx_c*3;
        pcx = pp[0]; pcy = pp[1]; pcz = pp[2];
        #pragma unroll
        for (int it = 0; it < 8; ++it) {
          int nh = __shfl(idx_c, 4*it + lq);
          xr[it] = *(const float4*)&x[(size_t)nh*C_IN + 4*l15];
        }
        int n1 = n0 + 1;  int nc1 = n1 < N_PTS ? n1 : N_PTS-1;
        idx_n = neighbors[nc1*H_NB + (lane & 31)];
        cnx = points[nc1*3+0]; cny = points[nc1*3+1]; cnz = points[nc1*3+2];
        const float* pq = points + (size_t)idx_n*3;
        pnx = pq[0]; pny = pq[1]; pnz = pq[2];
      }

      #pragma unroll 1
      for (int p = 0; p < PPW; ++p) {
        const int mpt = w*PPW + p;
        float rx = pcx - ccx, ry = pcy - ccy, rz = pcz - ccz;
        bf16x8 afrag;
        #pragma unroll
        for (int j = 0; j < 8; ++j) {
          int h = (lq << 3) + j;
          float dx = __shfl(rx, h) - kqx;
          float dy = __shfl(ry, h) - kqy;
          float dz = __shfl(rz, h) - kqz;
          float f  = 1.f - sqrtf(dx*dx + dy*dy + dz*dz);
          afrag[j] = (__bf16)(f > 0.f ? f : 0.f);
        }
        #pragma unroll
        for (int it = 0; it < 8; ++it) {
          float4 v = xr[it];
          unsigned lo = ((unsigned)bfbits(v.y) << 16) | bfbits(v.x);
          unsigned hi = ((unsigned)bfbits(v.w) << 16) | bfbits(v.z);
          int ei = XG_PLANE*(l15 >> 2) + XG_SUB*it + 16*lq + 4*(l15 & 3);
          uint2 val; val.x = lo; val.y = hi;
          *(uint2*)(xgw + ei) = val;
        }
        if (p + 1 < PPW) {
          #pragma unroll
          for (int it = 0; it < 8; ++it) {
            int nh = __shfl(idx_n, 4*it + lq);
            xr[it] = *(const float4*)&x[(size_t)nh*C_IN + 4*l15];
          }
        }
        if (p + 2 < PPW) {
          int n2 = base + w*PPW + p + 2;  int nc2 = n2 < N_PTS ? n2 : N_PTS-1;
          idx_nn = neighbors[nc2*H_NB + (lane & 31)];
          c2x = points[nc2*3+0]; c2y = points[nc2*3+1]; c2z = points[nc2*3+2];
        }
        asm volatile("s_waitcnt lgkmcnt(0)" ::: "memory");
        ushort8 bbr[4];
        #pragma unroll
        for (int ct = 0; ct < 4; ++ct) {
          #pragma unroll
          for (int j = 0; j < 8; ++j)
            bbr[ct][j] = xgw[XG_PLANE*ct + XG_SUB*(2*lq + (j>>2)) + 16*(j&3) + l15];
        }
        f32x4 acc[4] = {{0,0,0,0},{0,0,0,0},{0,0,0,0},{0,0,0,0}};
        #pragma unroll
        for (int ct = 0; ct < 4; ++ct)
          acc[ct] = __builtin_amdgcn_mfma_f32_16x16x32_bf16(
              afrag, __builtin_bit_cast(bf16x8, bbr[ct]), acc[ct], 0, 0, 0);
        #pragma unroll
        for (int ct = 0; ct < 4; ++ct) {
          #pragma unroll
          for (int r = 0; r < 4; ++r) {
            int k = 4*lq + r;
            if (k < K_KP)
              wf_lds[mpt*WFS + k*C_IN + ((ct ^ lq)*16) + l15] = bfbits(acc[ct][r]);
          }
        }
        if (p + 1 < PPW) {
          pcx = pnx; pcy = pny; pcz = pnz;
          ccx = cnx; ccy = cny; ccz = cnz;
          idx_c = idx_n; idx_n = idx_nn;
          cnx = c2x; cny = c2y; cnz = c2z;
          if (p + 2 < PPW) {
            const float* pq = points + (size_t)idx_n*3;
            pnx = pq[0]; pny = pq[1]; pnz = pq[2];
          }
        }
      }
    }

    __syncthreads();
    const int wd = w;
    f32x4 b00{0,0,0,0}, b01{0,0,0,0}, b10{0,0,0,0}, b11{0,0,0,0};
    const unsigned short* arow0 = &wf_lds[l15*WFS];
    const unsigned short* arow1 = arow0 + 16*WFS;
    const unsigned short* wrow0 = Wt + (size_t)(wd*32 + l15)*KC + lq*8;
    const unsigned short* wrow1 = wrow0 + (size_t)16*KC;
    #pragma unroll 6
    for (int ks = 0; ks < KC/32; ++ks) {
      int aoff = (ks*32 + lq*8) ^ ((((ks >> 1) >> 2) & 3) << 4);
      bf16x8 a0 = ld_bf8(arow0 + aoff);
      bf16x8 a1 = ld_bf8(arow1 + aoff);
      bf16x8 w0 = ld_bf8(wrow0 + ks*32);
      bf16x8 w1 = ld_bf8(wrow1 + ks*32);
      b00 = __builtin_amdgcn_mfma_f32_16x16x32_bf16(a0, w0, b00, 0, 0, 0);
      b01 = __builtin_amdgcn_mfma_f32_16x16x32_bf16(a0, w1, b01, 0, 0, 0);
      b10 = __builtin_amdgcn_mfma_f32_16x16x32_bf16(a1, w0, b10, 0, 0, 0);
      b11 = __builtin_amdgcn_mfma_f32_16x16x32_bf16(a1, w1, b11, 0, 0, 0);
    }
    float s0 = 0.f, q0 = 0.f, s1 = 0.f, q1 = 0.f;
    const int dcol0 = wd*32 + l15;
    #pragma unroll
    for (int mi = 0; mi < 2; ++mi) {
      const f32x4 A0 = mi ? b10 : b00;
      const f32x4 A1 = mi ? b11 : b01;
      #pragma unroll
      for (int r = 0; r < 4; ++r) {
        int n = base + mi*16 + 4*lq + r;
        if (n < N_PTS) {
          float v0 = A0[r], v1 = A1[r];
          out_pre[(size_t)n*C_OUT + dcol0]      = v0;
          out_pre[(size_t)n*C_OUT + dcol0 + 16] = v1;
          s0 += v0; q0 += v0*v0;
          s1 += v1; q1 += v1*v1;
        }
      }
    }
    s0 += __shfl_xor(s0, 16); s0 += __shfl_xor(s0, 32);
    q0 += __shfl_xor(q0, 16); q0 += __shfl_xor(q0, 32);
    s1 += __shfl_xor(s1, 16); s1 += __shfl_xor(s1, 32);
    q1 += __shfl_xor(q1, 16); q1 += __shfl_xor(q1, 32);
    if (lane < 16) {
      sh_sum[wd*32 + lane]      = s0;
      sh_sum[wd*32 + 16 + lane] = s1;
      sh_sq [wd*32 + lane]      = q0;
      sh_sq [wd*32 + 16 + lane] = q1;
    }
    __syncthreads();
    if (tid < C_OUT) {
      atomicAdd(&stats[tid],         sh_sum[tid]);
      atomicAdd(&stats[C_OUT + tid], sh_sq[tid]);
    }
  }
}

// ---- split GEMM: 3-buffer pipeline, raw s_barrier + counted vmcnt (R19-proven) ----
__global__ __launch_bounds__(256, 2) void gemm_kernel(
    const unsigned short* __restrict__ wfg,
    const unsigned short* __restrict__ Wt,
    float* __restrict__ out_pre,
    float* __restrict__ stats)
{
  __shared__ __align__(16) unsigned short Abuf[3][64*64];
  __shared__ __align__(16) unsigned short Bbuf[3][128*64];
  __shared__ float sh_sum[2][C_OUT];
  __shared__ float sh_sq [2][C_OUT];

  const int tid  = threadIdx.x;
  const int w    = tid >> 6;
  const int lane = tid & 63;
  const int l15  = lane & 15;
  const int lq   = lane >> 4;
  const int wm   = w >> 1;
  const int wn   = w & 1;
  const int m0   = blockIdx.x * 64;

  const int r8 = lane >> 3;
  const int cs = (lane & 7) ^ r8;

  auto stage = [&](int b, int kt){
    const int k0 = kt * 64;
    #pragma unroll
    for (int q = 0; q < 2; ++q) {
      int row = w*16 + q*8;
      gload16(wfg + (size_t)(m0 + row + r8)*KC + k0 + cs*8, &Abuf[b][row*64]);
    }
    #pragma unroll
    for (int q = 0; q < 4; ++q) {
      int row = w*32 + q*8;
      gload16(Wt + (size_t)(row + r8)*KC + k0 + cs*8, &Bbuf[b][row*64]);
    }
  };

  stage(0, 0);
  stage(1, 1);

  f32x4 acc[2][4] = {};
  const int NT = KC / 64;   // 15
  for (int ks = 0; ks < NT; ++ks) {
    if (ks + 1 < NT) {
      asm volatile("s_waitcnt vmcnt(6)" ::: "memory");
    } else {
      asm volatile("s_waitcnt vmcnt(0)" ::: "memory");
    }
    __builtin_amdgcn_sched_barrier(0);
    __builtin_amdgcn_s_barrier();
    asm volatile("" ::: "memory");
    if (ks + 2 < NT) stage((ks + 2) % 3, ks + 2);

    const unsigned short* A = Abuf[ks % 3];
    const unsigned short* B = Bbuf[ks % 3];
    #pragma unroll
    for (int kk = 0; kk < 2; ++kk) {
      const int cA = kk*4 + lq;
      bf16x8 af[2], bfr[4];
      #pragma unroll
      for (int mf = 0; mf < 2; ++mf) {
        int r = wm*32 + mf*16 + l15;
        af[mf] = ld_bf8(A + r*64 + ((cA ^ (r & 7)) * 8));
      }
      #pragma unroll
      for (int nf = 0; nf < 4; ++nf) {
        int r = wn*64 + nf*16 + l15;
        bfr[nf] = ld_bf8(B + r*64 + ((cA ^ (r & 7)) * 8));
      }
      #pragma unroll
      for (int mf = 0; mf < 2; ++mf)
        #pragma unroll
        for (int nf = 0; nf < 4; ++nf)
          acc[mf][nf] = __builtin_amdgcn_mfma_f32_16x16x32_bf16(af[mf], bfr[nf], acc[mf][nf], 0, 0, 0);
    }
  }

  float ssum[4] = {0,0,0,0}, ssq[4] = {0,0,0,0};
  #pragma unroll
  for (int mf = 0; mf < 2; ++mf) {
    #pragma unroll
    for (int nf = 0; nf < 4; ++nf) {
      #pragma unroll
      for (int r = 0; r < 4; ++r) {
        int m = m0 + wm*32 + mf*16 + 4*lq + r;
        if (m < N_PTS) {
          float v = acc[mf][nf][r];
          out_pre[(size_t)m*C_OUT + wn*64 + nf*16 + l15] = v;
          ssum[nf] += v; ssq[nf] += v*v;
        }
      }
    }
  }
  #pragma unroll
  for (int nf = 0; nf < 4; ++nf) {
    ssum[nf] += __shfl_xor(ssum[nf], 16); ssum[nf] += __shfl_xor(ssum[nf], 32);
    ssq[nf]  += __shfl_xor(ssq[nf], 16);  ssq[nf]  += __shfl_xor(ssq[nf], 32);
  }
  if (lane < 16) {
    #pragma unroll
    for (int nf = 0; nf < 4; ++nf) {
      sh_sum[wm][wn*64 + nf*16 + lane] = ssum[nf];
      sh_sq [wm][wn*64 + nf*16 + lane] = ssq[nf];
    }
  }
  __syncthreads();
  if (tid < C_OUT) {
    atomicAdd(&stats[tid],         sh_sum[0][tid] + sh_sum[1][tid]);
    atomicAdd(&stats[C_OUT + tid], sh_sq[0][tid] + sh_sq[1][tid]);
  }
}

// ---- bn_lrelu with inline finalize ----
__global__ __launch_bounds__(256) void bn_lrelu_kernel(float* __restrict__ out,
                                                       const float* __restrict__ stats,
                                                       const float* __restrict__ gamma,
                                                       const float* __restrict__ beta){
  __shared__ float sc_s[C_OUT], sh_s[C_OUT];
  if (threadIdx.x < C_OUT) {
    int d = threadIdx.x;
    float mean = stats[d] * (1.f/N_PTS);
    float var  = stats[C_OUT+d] * (1.f/N_PTS) - mean*mean;
    var = var > 0.f ? var : 0.f;
    float inv = rsqrtf(var + BN_EPS);
    float sc  = inv * gamma[d];
    sc_s[d] = sc;
    sh_s[d] = beta[d] - mean * sc;
  }
  __syncthreads();
  const int total4 = N_PTS*C_OUT/4;
  const float4* scp = (const float4*)sc_s;
  const float4* shp = (const float4*)sh_s;
  float4* o4 = (float4*)out;
  for (int t = blockIdx.x*blockDim.x + threadIdx.x; t < total4; t += gridDim.x*blockDim.x) {
    int col4 = t & (C_OUT/4 - 1);
    float4 v = o4[t];
    float4 sc = scp[col4], sh = shp[col4];
    float y0 = v.x*sc.x + sh.x;
    float y1 = v.y*sc.y + sh.y;
    float y2 = v.z*sc.z + sh.z;
    float y3 = v.w*sc.w + sh.w;
    v.x = y0 > 0.f ? y0 : SLOPE*y0;
    v.y = y1 > 0.f ? y1 : SLOPE*y1;
    v.z = y2 > 0.f ? y2 : SLOPE*y2;
    v.w = y3 > 0.f ? y3 : SLOPE*y3;
    o4[t] = v;
  }
}

extern "C" void kernel_launch(void* const* d_in, const int* in_sizes, int n_in,
                              void* d_out, int out_size, void* d_ws, size_t ws_size,
                              hipStream_t stream) {
  const float* points    = (const float*)d_in[0];
  const float* x         = (const float*)d_in[1];
  const int*   neighbors = (const int*)d_in[2];
  const float* kpts      = (const float*)d_in[3];
  const float* weights   = (const float*)d_in[4];
  const float* gamma     = (const float*)d_in[5];
  const float* beta      = (const float*)d_in[6];
  float* out = (float*)d_out;
  float* ws  = (float*)d_ws;
  // ws layout: [0,1024) stats | [1024,2048) spare | [2048,+245760) Wt | then wfg (96 MB)
  unsigned short* Wt  = (unsigned short*)((char*)d_ws + 2048);
  unsigned short* wfg = (unsigned short*)((char*)d_ws + 2048 + 245760);
  // split-path xbf lives in d_out's front 6.4 MB (dead until gemm overwrites)
  unsigned short* xbf = (unsigned short*)d_out;
  const size_t need = 2048u + 245760u + (size_t)M_PAD*KC*2u;
  const bool split = (ws_size >= need);

  hipLaunchKernelGGL(prep_kernel, dim3(KC/32, C_OUT/32), dim3(256), 0, stream,
                     weights, Wt, ws);
  const int nblocks = (N_PTS + M_TILE - 1) / M_TILE;   // 1563
  if (split) {
    hipLaunchKernelGGL(xprep_kernel, dim3((N_PTS*C_IN/8 + 255)/256), dim3(256), 0, stream,
                       x, xbf);
    kpconv_core<true><<<dim3(nblocks), dim3(256), 0, stream>>>(
        points, x, xbf, neighbors, kpts, Wt, wfg, out, ws);
    gemm_kernel<<<dim3(M_PAD/64), dim3(256), 0, stream>>>(wfg, Wt, out, ws);
  } else {
    kpconv_core<false><<<dim3(nblocks), dim3(256), 0, stream>>>(
        points, x, xbf, neighbors, kpts, Wt, wfg, out, ws);
  }
  hipLaunchKernelGGL(bn_lrelu_kernel, dim3(2048), dim3(256), 0, stream, out, ws, gamma, beta);
}

// Round 25
// 106.840 us; speedup vs baseline: 1.6227x; 1.0436x over previous
//
#include <hip/hip_runtime.h>
#include <hip/hip_bf16.h>

#define N_PTS 50000
#define H_NB 32
#define K_KP 15
#define C_IN 64
#define C_OUT 128
#define KC 960           // K_KP * C_IN
#define M_PAD 50048      // padded wf rows (mult of 64)
#define M_TILE 32
#define PPW 8            // points per wave (4 waves/block)
#define WFS 968          // fused-path wf_lds row stride
#define XG_SUB 68        // fused-path xg strides
#define XG_PLANE 552
#define XG_WAVE (4*XG_PLANE)
#define XPB ((N_PTS*C_IN/8 + 255)/256)   // x-convert blocks = 1563
#define BN_EPS 1e-5f
#define SLOPE 0.2f

typedef __attribute__((ext_vector_type(8))) __bf16 bf16x8;
typedef __attribute__((ext_vector_type(8))) unsigned short ushort8;
typedef __attribute__((ext_vector_type(4))) float f32x4;

__device__ __forceinline__ unsigned short bfbits(float f){
  return __builtin_bit_cast(unsigned short, (__bf16)f);
}
__device__ __forceinline__ bf16x8 ld_bf8(const unsigned short* p){
  return __builtin_bit_cast(bf16x8, *(const uint4*)p);
}
// async global->LDS DMA, 16B per lane; global source address is PER-LANE (gather-capable)
__device__ __forceinline__ void gload16(const void* g, void* l){
  __builtin_amdgcn_global_load_lds(
      (__attribute__((address_space(1))) void*)(g),
      (__attribute__((address_space(3))) void*)(l), 16, 0, 0);
}

// ---- prep (merged, R22-verified): blocks [0,XPB) convert x f32->bf16 RNE;
//      blocks [XPB, XPB+120) transpose W -> Wt bf16; first W-block zeros stats ----
__global__ __launch_bounds__(256) void prep_kernel(const float* __restrict__ W,
                                                   const float* __restrict__ x,
                                                   unsigned short* __restrict__ Wt,
                                                   unsigned short* __restrict__ xbf,
                                                   float* __restrict__ stats){
  __shared__ float tile[32][33];
  int b = blockIdx.x;
  if (b < XPB) {
    int t = b*256 + threadIdx.x;
    if (t < N_PTS*C_IN/8) {
      float4 a = ((const float4*)x)[2*t], v = ((const float4*)x)[2*t+1];
      ushort8 o;
      o[0]=bfbits(a.x); o[1]=bfbits(a.y); o[2]=bfbits(a.z); o[3]=bfbits(a.w);
      o[4]=bfbits(v.x); o[5]=bfbits(v.y); o[6]=bfbits(v.z); o[7]=bfbits(v.w);
      *(ushort8*)(xbf + 8*t) = o;
    }
    return;
  }
  b -= XPB;
  const int kc0 = (b % (KC/32)) * 32, d0 = (b / (KC/32)) * 32;
  if (kc0 == 0 && d0 == 0 && threadIdx.x < 2*C_OUT)
    stats[threadIdx.x] = 0.f;
  const int r = threadIdx.x >> 5, c = threadIdx.x & 31;
  #pragma unroll
  for (int rr = 0; rr < 4; ++rr) {
    int row = rr*8 + r;
    tile[row][c] = W[(size_t)(kc0+row)*C_OUT + d0 + c];
  }
  __syncthreads();
  #pragma unroll
  for (int rr = 0; rr < 4; ++rr) {
    int dr = rr*8 + r;
    Wt[(size_t)(d0+dr)*KC + kc0 + c] = bfbits(tile[c][dr]);
  }
}

// ---- core: Phase A. SPLIT: DMA-gathered bf16 x, statically-counted vmcnt pipeline (R24).
//      !SPLIT: legacy fused (R7-verified). ----
// NOTE: SPLIT bound MUST stay 4 — bounds 5/6/8 (R22/R17/R14) all spill to scratch.
template<bool SPLIT>
__global__ __launch_bounds__(256, SPLIT ? 4 : 2) void kpconv_core(
    const float* __restrict__ points,
    const float* __restrict__ x,            // f32 x (fused path)
    const unsigned short* __restrict__ xbf, // bf16 x (split path)
    const int*   __restrict__ neighbors,
    const float* __restrict__ kpts,
    const unsigned short* __restrict__ Wt,
    unsigned short* __restrict__ wfg,
    float* __restrict__ out_pre,
    float* __restrict__ stats)
{
  __shared__ __align__(16) unsigned short xg[SPLIT ? 4*4096 : 4*XG_WAVE];
  __shared__ unsigned short wf_lds[SPLIT ? 8 : M_TILE*WFS];
  __shared__ float sh_sum[SPLIT ? 1 : C_OUT];
  __shared__ float sh_sq [SPLIT ? 1 : C_OUT];

  const int tid  = threadIdx.x;
  const int w    = tid >> 6;
  const int lane = tid & 63;
  const int l15  = lane & 15;
  const int lq   = lane >> 4;
  const int base = blockIdx.x * M_TILE;

  float kqx, kqy, kqz;
  if (l15 < K_KP) { kqx = kpts[l15*3+0]; kqy = kpts[l15*3+1]; kqz = kpts[l15*3+2]; }
  else            { kqx = 1e3f; kqy = 0.f; kqz = 0.f; }

  if constexpr (SPLIT) {
    // per-wave double buffer 2 x 2048 elems; row h, phys chunk pc = logical pc^(2*(h>>3))
    unsigned short* xb0 = &xg[w * 4096];
    unsigned short* xb1 = xb0 + 2048;
    const int r8 = lane >> 3;
    const int pc = lane & 7;

    auto dma_point = [&](unsigned short* buf, int idx){
      #pragma unroll
      for (int it = 0; it < 4; ++it) {
        int nh = __shfl(idx, 8*it + r8);
        const unsigned short* src = xbf + (size_t)nh*C_IN + ((pc ^ (2*it)) * 8);
        gload16(src, buf + it*512);
      }
    };

    // ---- prologue: hoist all idx/centers (static arrays under full unroll) ----
    int   idxs[PPW];
    float cx[PPW], cy[PPW], cz[PPW];
    #pragma unroll
    for (int i = 0; i < PPW; ++i) {
      int ni = base + w*PPW + i;
      int nc = ni < N_PTS ? ni : N_PTS-1;
      idxs[i] = neighbors[nc*H_NB + (lane & 31)];
      cx[i] = points[nc*3+0]; cy[i] = points[nc*3+1]; cz[i] = points[nc*3+2];
    }
    float p0x, p0y, p0z, p1x, p1y, p1z;
    { const float* pp = points + (size_t)idxs[0]*3; p0x = pp[0]; p0y = pp[1]; p0z = pp[2]; }
    { const float* pq = points + (size_t)idxs[1]*3; p1x = pq[0]; p1y = pq[1]; p1z = pq[2]; }
    __builtin_amdgcn_sched_barrier(0);
    dma_point(xb0, idxs[0]);
    dma_point(xb1, idxs[1]);
    __builtin_amdgcn_sched_barrier(0);

    #pragma unroll
    for (int p = 0; p < PPW; ++p) {
      unsigned short* cur = (p & 1) ? xb1 : xb0;

      // influence A-frag from npos(p) and hoisted center[p] (VALU only)
      float rx = p0x - cx[p], ry = p0y - cy[p], rz = p0z - cz[p];
      bf16x8 afrag;
      #pragma unroll
      for (int j = 0; j < 8; ++j) {
        int h = (lq << 3) + j;
        float dx = __shfl(rx, h) - kqx;
        float dy = __shfl(ry, h) - kqy;
        float dz = __shfl(rz, h) - kqz;
        float f  = 1.f - sqrtf(dx*dx + dy*dy + dz*dz);
        afrag[j] = (__bf16)(f > 0.f ? f : 0.f);
      }

      // statically-counted wait: younger-than-DMA(p) = stores(2)+npos(>=1)+DMA(p+1)(4) = 7 min
      if (p == 0)            { asm volatile("s_waitcnt vmcnt(4)" ::: "memory"); }
      else if (p == PPW - 1) { asm volatile("s_waitcnt vmcnt(0)" ::: "memory"); }
      else                   { asm volatile("s_waitcnt vmcnt(7)" ::: "memory"); }
      __builtin_amdgcn_sched_barrier(0);

      // B-frag reads (conflict-free, measured 400K) + MFMA
      f32x4 acc[4] = {{0,0,0,0},{0,0,0,0},{0,0,0,0},{0,0,0,0}};
      #pragma unroll
      for (int ct = 0; ct < 4; ++ct) {
        ushort8 b;
        const int pcr = ((2*ct + (l15 >> 3)) ^ (2*lq)) * 8 + (l15 & 7);
        #pragma unroll
        for (int j = 0; j < 8; ++j)
          b[j] = cur[lq*512 + j*64 + pcr];
        acc[ct] = __builtin_amdgcn_mfma_f32_16x16x32_bf16(
            afrag, __builtin_bit_cast(bf16x8, b), acc[ct], 0, 0, 0);
      }

      // bounce acc -> cur (k-stride 72), then UNCONDITIONAL coalesced stores (rows < M_PAD)
      const int n_out = base + w*PPW + p;   // <= 50015 < M_PAD; rows >= N_PTS masked downstream
      #pragma unroll
      for (int ct = 0; ct < 4; ++ct) {
        #pragma unroll
        for (int r = 0; r < 4; ++r) {
          int k = 4*lq + r;
          if (k < K_KP)
            cur[72*k + ct*16 + l15] = bfbits(acc[ct][r]);
        }
      }
      asm volatile("s_waitcnt lgkmcnt(0)" ::: "memory");
      {
        uint4 c0 = *(const uint4*)(cur + 72*(lane>>3) + 8*(lane&7));
        *(uint4*)(wfg + (size_t)n_out*KC + lane*8) = c0;
        if (lane < 56) {
          int ch = 64 + lane;
          uint4 c1 = *(const uint4*)(cur + 72*(ch>>3) + 8*(ch&7));
          *(uint4*)(wfg + (size_t)n_out*KC + ch*8) = c1;
        }
      }
      asm volatile("s_waitcnt lgkmcnt(0)" ::: "memory");
      __builtin_amdgcn_sched_barrier(0);

      // rotation: npos(p+2) then DMA(p+2) into cur (order pinned)
      p0x = p1x; p0y = p1y; p0z = p1z;
      if (p + 2 < PPW) {
        const float* pq = points + (size_t)idxs[p+2]*3;
        p1x = pq[0]; p1y = pq[1]; p1z = pq[2];
        __builtin_amdgcn_sched_barrier(0);
        dma_point(cur, idxs[p+2]);
        __builtin_amdgcn_sched_barrier(0);
      }
    }
  } else {
    // ------------- legacy fused path (R7-verified), f32 x -------------
    unsigned short* xgw = &xg[w * XG_WAVE];
    {
      int   idx_c, idx_n = 0, idx_nn = 0;
      float pcx, pcy, pcz, pnx = 0, pny = 0, pnz = 0;
      float ccx, ccy, ccz, cnx = 0, cny = 0, cnz = 0, c2x = 0, c2y = 0, c2z = 0;
      float4 xr[8];
      {
        int n0 = base + w*PPW;  int nc0 = n0 < N_PTS ? n0 : N_PTS-1;
        idx_c = neighbors[nc0*H_NB + (lane & 31)];
        ccx = points[nc0*3+0]; ccy = points[nc0*3+1]; ccz = points[nc0*3+2];
        const float* pp = points + (size_t)idx_c*3;
        pcx = pp[0]; pcy = pp[1]; pcz = pp[2];
        #pragma unroll
        for (int it = 0; it < 8; ++it) {
          int nh = __shfl(idx_c, 4*it + lq);
          xr[it] = *(const float4*)&x[(size_t)nh*C_IN + 4*l15];
        }
        int n1 = n0 + 1;  int nc1 = n1 < N_PTS ? n1 : N_PTS-1;
        idx_n = neighbors[nc1*H_NB + (lane & 31)];
        cnx = points[nc1*3+0]; cny = points[nc1*3+1]; cnz = points[nc1*3+2];
        const float* pq = points + (size_t)idx_n*3;
        pnx = pq[0]; pny = pq[1]; pnz = pq[2];
      }

      #pragma unroll 1
      for (int p = 0; p < PPW; ++p) {
        const int mpt = w*PPW + p;
        float rx = pcx - ccx, ry = pcy - ccy, rz = pcz - ccz;
        bf16x8 afrag;
        #pragma unroll
        for (int j = 0; j < 8; ++j) {
          int h = (lq << 3) + j;
          float dx = __shfl(rx, h) - kqx;
          float dy = __shfl(ry, h) - kqy;
          float dz = __shfl(rz, h) - kqz;
          float f  = 1.f - sqrtf(dx*dx + dy*dy + dz*dz);
          afrag[j] = (__bf16)(f > 0.f ? f : 0.f);
        }
        #pragma unroll
        for (int it = 0; it < 8; ++it) {
          float4 v = xr[it];
          unsigned lo = ((unsigned)bfbits(v.y) << 16) | bfbits(v.x);
          unsigned hi = ((unsigned)bfbits(v.w) << 16) | bfbits(v.z);
          int ei = XG_PLANE*(l15 >> 2) + XG_SUB*it + 16*lq + 4*(l15 & 3);
          uint2 val; val.x = lo; val.y = hi;
          *(uint2*)(xgw + ei) = val;
        }
        if (p + 1 < PPW) {
          #pragma unroll
          for (int it = 0; it < 8; ++it) {
            int nh = __shfl(idx_n, 4*it + lq);
            xr[it] = *(const float4*)&x[(size_t)nh*C_IN + 4*l15];
          }
        }
        if (p + 2 < PPW) {
          int n2 = base + w*PPW + p + 2;  int nc2 = n2 < N_PTS ? n2 : N_PTS-1;
          idx_nn = neighbors[nc2*H_NB + (lane & 31)];
          c2x = points[nc2*3+0]; c2y = points[nc2*3+1]; c2z = points[nc2*3+2];
        }
        asm volatile("s_waitcnt lgkmcnt(0)" ::: "memory");
        ushort8 bbr[4];
        #pragma unroll
        for (int ct = 0; ct < 4; ++ct) {
          #pragma unroll
          for (int j = 0; j < 8; ++j)
            bbr[ct][j] = xgw[XG_PLANE*ct + XG_SUB*(2*lq + (j>>2)) + 16*(j&3) + l15];
        }
        f32x4 acc[4] = {{0,0,0,0},{0,0,0,0},{0,0,0,0},{0,0,0,0}};
        #pragma unroll
        for (int ct = 0; ct < 4; ++ct)
          acc[ct] = __builtin_amdgcn_mfma_f32_16x16x32_bf16(
              afrag, __builtin_bit_cast(bf16x8, bbr[ct]), acc[ct], 0, 0, 0);
        #pragma unroll
        for (int ct = 0; ct < 4; ++ct) {
          #pragma unroll
          for (int r = 0; r < 4; ++r) {
            int k = 4*lq + r;
            if (k < K_KP)
              wf_lds[mpt*WFS + k*C_IN + ((ct ^ lq)*16) + l15] = bfbits(acc[ct][r]);
          }
        }
        if (p + 1 < PPW) {
          pcx = pnx; pcy = pny; pcz = pnz;
          ccx = cnx; ccy = cny; ccz = cnz;
          idx_c = idx_n; idx_n = idx_nn;
          cnx = c2x; cny = c2y; cnz = c2z;
          if (p + 2 < PPW) {
            const float* pq = points + (size_t)idx_n*3;
            pnx = pq[0]; pny = pq[1]; pnz = pq[2];
          }
        }
      }
    }

    __syncthreads();
    const int wd = w;
    f32x4 b00{0,0,0,0}, b01{0,0,0,0}, b10{0,0,0,0}, b11{0,0,0,0};
    const unsigned short* arow0 = &wf_lds[l15*WFS];
    const unsigned short* arow1 = arow0 + 16*WFS;
    const unsigned short* wrow0 = Wt + (size_t)(wd*32 + l15)*KC + lq*8;
    const unsigned short* wrow1 = wrow0 + (size_t)16*KC;
    #pragma unroll 6
    for (int ks = 0; ks < KC/32; ++ks) {
      int aoff = (ks*32 + lq*8) ^ ((((ks >> 1) >> 2) & 3) << 4);
      bf16x8 a0 = ld_bf8(arow0 + aoff);
      bf16x8 a1 = ld_bf8(arow1 + aoff);
      bf16x8 w0 = ld_bf8(wrow0 + ks*32);
      bf16x8 w1 = ld_bf8(wrow1 + ks*32);
      b00 = __builtin_amdgcn_mfma_f32_16x16x32_bf16(a0, w0, b00, 0, 0, 0);
      b01 = __builtin_amdgcn_mfma_f32_16x16x32_bf16(a0, w1, b01, 0, 0, 0);
      b10 = __builtin_amdgcn_mfma_f32_16x16x32_bf16(a1, w0, b10, 0, 0, 0);
      b11 = __builtin_amdgcn_mfma_f32_16x16x32_bf16(a1, w1, b11, 0, 0, 0);
    }
    float s0 = 0.f, q0 = 0.f, s1 = 0.f, q1 = 0.f;
    const int dcol0 = wd*32 + l15;
    #pragma unroll
    for (int mi = 0; mi < 2; ++mi) {
      const f32x4 A0 = mi ? b10 : b00;
      const f32x4 A1 = mi ? b11 : b01;
      #pragma unroll
      for (int r = 0; r < 4; ++r) {
        int n = base + mi*16 + 4*lq + r;
        if (n < N_PTS) {
          float v0 = A0[r], v1 = A1[r];
          out_pre[(size_t)n*C_OUT + dcol0]      = v0;
          out_pre[(size_t)n*C_OUT + dcol0 + 16] = v1;
          s0 += v0; q0 += v0*v0;
          s1 += v1; q1 += v1*v1;
        }
      }
    }
    s0 += __shfl_xor(s0, 16); s0 += __shfl_xor(s0, 32);
    q0 += __shfl_xor(q0, 16); q0 += __shfl_xor(q0, 32);
    s1 += __shfl_xor(s1, 16); s1 += __shfl_xor(s1, 32);
    q1 += __shfl_xor(q1, 16); q1 += __shfl_xor(q1, 32);
    if (lane < 16) {
      sh_sum[wd*32 + lane]      = s0;
      sh_sum[wd*32 + 16 + lane] = s1;
      sh_sq [wd*32 + lane]      = q0;
      sh_sq [wd*32 + 16 + lane] = q1;
    }
    __syncthreads();
    if (tid < C_OUT) {
      atomicAdd(&stats[tid],         sh_sum[tid]);
      atomicAdd(&stats[C_OUT + tid], sh_sq[tid]);
    }
  }
}

// ---- split GEMM: 3-buffer pipeline, raw s_barrier + counted vmcnt (R19-proven) ----
__global__ __launch_bounds__(256, 2) void gemm_kernel(
    const unsigned short* __restrict__ wfg,
    const unsigned short* __restrict__ Wt,
    float* __restrict__ out_pre,
    float* __restrict__ stats)
{
  __shared__ __align__(16) unsigned short Abuf[3][64*64];
  __shared__ __align__(16) unsigned short Bbuf[3][128*64];
  __shared__ float sh_sum[2][C_OUT];
  __shared__ float sh_sq [2][C_OUT];

  const int tid  = threadIdx.x;
  const int w    = tid >> 6;
  const int lane = tid & 63;
  const int l15  = lane & 15;
  const int lq   = lane >> 4;
  const int wm   = w >> 1;
  const int wn   = w & 1;
  const int m0   = blockIdx.x * 64;

  const int r8 = lane >> 3;
  const int cs = (lane & 7) ^ r8;

  auto stage = [&](int b, int kt){
    const int k0 = kt * 64;
    #pragma unroll
    for (int q = 0; q < 2; ++q) {
      int row = w*16 + q*8;
      gload16(wfg + (size_t)(m0 + row + r8)*KC + k0 + cs*8, &Abuf[b][row*64]);
    }
    #pragma unroll
    for (int q = 0; q < 4; ++q) {
      int row = w*32 + q*8;
      gload16(Wt + (size_t)(row + r8)*KC + k0 + cs*8, &Bbuf[b][row*64]);
    }
  };

  stage(0, 0);
  stage(1, 1);

  f32x4 acc[2][4] = {};
  const int NT = KC / 64;   // 15
  for (int ks = 0; ks < NT; ++ks) {
    if (ks + 1 < NT) {
      asm volatile("s_waitcnt vmcnt(6)" ::: "memory");
    } else {
      asm volatile("s_waitcnt vmcnt(0)" ::: "memory");
    }
    __builtin_amdgcn_sched_barrier(0);
    __builtin_amdgcn_s_barrier();
    asm volatile("" ::: "memory");
    if (ks + 2 < NT) stage((ks + 2) % 3, ks + 2);

    const unsigned short* A = Abuf[ks % 3];
    const unsigned short* B = Bbuf[ks % 3];
    #pragma unroll
    for (int kk = 0; kk < 2; ++kk) {
      const int cA = kk*4 + lq;
      bf16x8 af[2], bfr[4];
      #pragma unroll
      for (int mf = 0; mf < 2; ++mf) {
        int r = wm*32 + mf*16 + l15;
        af[mf] = ld_bf8(A + r*64 + ((cA ^ (r & 7)) * 8));
      }
      #pragma unroll
      for (int nf = 0; nf < 4; ++nf) {
        int r = wn*64 + nf*16 + l15;
        bfr[nf] = ld_bf8(B + r*64 + ((cA ^ (r & 7)) * 8));
      }
      #pragma unroll
      for (int mf = 0; mf < 2; ++mf)
        #pragma unroll
        for (int nf = 0; nf < 4; ++nf)
          acc[mf][nf] = __builtin_amdgcn_mfma_f32_16x16x32_bf16(af[mf], bfr[nf], acc[mf][nf], 0, 0, 0);
    }
  }

  float ssum[4] = {0,0,0,0}, ssq[4] = {0,0,0,0};
  #pragma unroll
  for (int mf = 0; mf < 2; ++mf) {
    #pragma unroll
    for (int nf = 0; nf < 4; ++nf) {
      #pragma unroll
      for (int r = 0; r < 4; ++r) {
        int m = m0 + wm*32 + mf*16 + 4*lq + r;
        if (m < N_PTS) {
          float v = acc[mf][nf][r];
          out_pre[(size_t)m*C_OUT + wn*64 + nf*16 + l15] = v;
          ssum[nf] += v; ssq[nf] += v*v;
        }
      }
    }
  }
  #pragma unroll
  for (int nf = 0; nf < 4; ++nf) {
    ssum[nf] += __shfl_xor(ssum[nf], 16); ssum[nf] += __shfl_xor(ssum[nf], 32);
    ssq[nf]  += __shfl_xor(ssq[nf], 16);  ssq[nf]  += __shfl_xor(ssq[nf], 32);
  }
  if (lane < 16) {
    #pragma unroll
    for (int nf = 0; nf < 4; ++nf) {
      sh_sum[wm][wn*64 + nf*16 + lane] = ssum[nf];
      sh_sq [wm][wn*64 + nf*16 + lane] = ssq[nf];
    }
  }
  __syncthreads();
  if (tid < C_OUT) {
    atomicAdd(&stats[tid],         sh_sum[0][tid] + sh_sum[1][tid]);
    atomicAdd(&stats[C_OUT + tid], sh_sq[0][tid] + sh_sq[1][tid]);
  }
}

// ---- bn_lrelu with inline finalize ----
__global__ __launch_bounds__(256) void bn_lrelu_kernel(float* __restrict__ out,
                                                       const float* __restrict__ stats,
                                                       const float* __restrict__ gamma,
                                                       const float* __restrict__ beta){
  __shared__ float sc_s[C_OUT], sh_s[C_OUT];
  if (threadIdx.x < C_OUT) {
    int d = threadIdx.x;
    float mean = stats[d] * (1.f/N_PTS);
    float var  = stats[C_OUT+d] * (1.f/N_PTS) - mean*mean;
    var = var > 0.f ? var : 0.f;
    float inv = rsqrtf(var + BN_EPS);
    float sc  = inv * gamma[d];
    sc_s[d] = sc;
    sh_s[d] = beta[d] - mean * sc;
  }
  __syncthreads();
  const int total4 = N_PTS*C_OUT/4;
  const float4* scp = (const float4*)sc_s;
  const float4* shp = (const float4*)sh_s;
  float4* o4 = (float4*)out;
  for (int t = blockIdx.x*blockDim.x + threadIdx.x; t < total4; t += gridDim.x*blockDim.x) {
    int col4 = t & (C_OUT/4 - 1);
    float4 v = o4[t];
    float4 sc = scp[col4], sh = shp[col4];
    float y0 = v.x*sc.x + sh.x;
    float y1 = v.y*sc.y + sh.y;
    float y2 = v.z*sc.z + sh.z;
    float y3 = v.w*sc.w + sh.w;
    v.x = y0 > 0.f ? y0 : SLOPE*y0;
    v.y = y1 > 0.f ? y1 : SLOPE*y1;
    v.z = y2 > 0.f ? y2 : SLOPE*y2;
    v.w = y3 > 0.f ? y3 : SLOPE*y3;
    o4[t] = v;
  }
}

extern "C" void kernel_launch(void* const* d_in, const int* in_sizes, int n_in,
                              void* d_out, int out_size, void* d_ws, size_t ws_size,
                              hipStream_t stream) {
  const float* points    = (const float*)d_in[0];
  const float* x         = (const float*)d_in[1];
  const int*   neighbors = (const int*)d_in[2];
  const float* kpts      = (const float*)d_in[3];
  const float* weights   = (const float*)d_in[4];
  const float* gamma     = (const float*)d_in[5];
  const float* beta      = (const float*)d_in[6];
  float* out = (float*)d_out;
  float* ws  = (float*)d_ws;
  // ws layout: [0,1024) stats | [1024,2048) spare | [2048,+245760) Wt | then wfg (96 MB)
  unsigned short* Wt  = (unsigned short*)((char*)d_ws + 2048);
  unsigned short* wfg = (unsigned short*)((char*)d_ws + 2048 + 245760);
  // split-path xbf lives in d_out's front 6.4 MB (dead until gemm overwrites)
  unsigned short* xbf = (unsigned short*)d_out;
  const size_t need = 2048u + 245760u + (size_t)M_PAD*KC*2u;
  const bool split = (ws_size >= need);

  const int nblocks = (N_PTS + M_TILE - 1) / M_TILE;   // 1563
  hipLaunchKernelGGL(prep_kernel, dim3(XPB + (KC/32)*(C_OUT/32)), dim3(256), 0, stream,
                     weights, x, Wt, xbf, ws);
  if (split) {
    kpconv_core<true><<<dim3(nblocks), dim3(256), 0, stream>>>(
        points, x, xbf, neighbors, kpts, Wt, wfg, out, ws);
    gemm_kernel<<<dim3(M_PAD/64), dim3(256), 0, stream>>>(wfg, Wt, out, ws);
  } else {
    kpconv_core<false><<<dim3(nblocks), dim3(256), 0, stream>>>(
        points, x, xbf, neighbors, kpts, Wt, wfg, out, ws);
  }
  hipLaunchKernelGGL(bn_lrelu_kernel, dim3(2048), dim3(256), 0, stream, out, ws, gamma, beta);
}